// Round 3
// baseline (384.849 us; speedup 1.0000x reference)
//
#include <hip/hip_runtime.h>

#define DEV_INLINE __device__ __forceinline__

constexpr int Nn   = 10000;     // nodes per batch
constexpr int NT   = 20000;     // B*N
constexpr int Me   = 320000;    // template edges
constexpr int Ee   = 2*Me + NT; // 660000 total edges
constexpr int NB   = (NT + 255) / 256;  // scan blocks = 79
constexpr float NEG = 0.2f;

DEV_INLINE float leaky(float x){ return x >= 0.f ? x : NEG*x; }

DEV_INLINE void edge_sd(int e, const int* __restrict__ eidx, int& s, int& d){
  if (e < 2*Me){
    int b = (e >= Me) ? 1 : 0;
    int t = e - b*Me;
    s = eidx[t]      + b*Nn;
    d = eidx[Me + t] + b*Nn;
  } else {
    s = e - 2*Me; d = s;
  }
}

// ---------------- style MLP + style @ gw0[64:,:] ----------------
__global__ __launch_bounds__(512) void k_style(const float* __restrict__ z,
    const float* __restrict__ w1, const float* __restrict__ b1,
    const float* __restrict__ w2, const float* __restrict__ b2,
    const float* __restrict__ w3, const float* __restrict__ b3,
    const float* __restrict__ gw0, float* __restrict__ styleW0){
  __shared__ float zl[2][128];
  __shared__ float s1[2][256];
  __shared__ float s2[2][512];
  __shared__ float st[2][128];
  int t = threadIdx.x;
  if (t < 256) zl[t>>7][t&127] = z[t];
  __syncthreads();
  { int b = t>>8, j = t&255; float acc = b1[j];
    for (int k=0;k<128;k++) acc += zl[b][k]*w1[k*256+j];
    s1[b][j] = leaky(acc); }
  __syncthreads();
  { int j = t;
    for (int b=0;b<2;b++){ float acc = b2[j];
      for (int k=0;k<256;k++) acc += s1[b][k]*w2[k*512+j];
      s2[b][j] = leaky(acc); } }
  __syncthreads();
  if (t < 256){ int b=t>>7, j=t&127; float acc=b3[j];
    for (int k=0;k<512;k++) acc += s2[b][k]*w3[k*128+j];
    st[b][j] = acc; }
  __syncthreads();
  if (t < 256){ int b=t>>7, j=t&127; float acc=0.f;
    for (int k=0;k<128;k++) acc += st[b][k]*gw0[(64+k)*128 + j];
    styleW0[b*128+j] = acc; }
}

// ---------------- ht0 = x @ gw0[:64,:] + styleW0[b]  (both batches) ----------------
__global__ __launch_bounds__(256) void k_ht0(const float* __restrict__ x,
    const float* __restrict__ gw0, const float* __restrict__ styleW0,
    float* __restrict__ ht0){
  __shared__ float wl[64][128];
  __shared__ float xl[32][65];   // padded: kill 16-way bank conflict
  __shared__ float sw[2][128];
  int t = threadIdx.x;
  for (int i=t; i<64*128; i+=256) wl[i>>7][i&127] = gw0[i];
  if (t < 256) sw[t>>7][t&127] = styleW0[t];
  int row0 = blockIdx.x*32;
  for (int i=t; i<32*64; i+=256){
    int r = i>>6, c = i&63; int gr = row0 + r;
    xl[r][c] = (gr < Nn) ? x[gr*64 + c] : 0.f;
  }
  __syncthreads();
  int c = t & 127, rh = t >> 7;
  float acc[16];
  #pragma unroll
  for (int i=0;i<16;i++) acc[i]=0.f;
  for (int k=0;k<64;k++){
    float w = wl[k][c];
    #pragma unroll
    for (int i=0;i<16;i++) acc[i] += xl[rh+2*i][k]*w;
  }
  float s0 = sw[0][c], s1 = sw[1][c];
  #pragma unroll
  for (int i=0;i<16;i++){
    int gr = row0 + rh + 2*i;
    if (gr < Nn){
      ht0[gr*128 + c]        = acc[i] + s0;
      ht0[(Nn+gr)*128 + c]   = acc[i] + s1;
    }
  }
}

// ---------------- generic tiled matmul: out[M,LDO] = A[M,K] @ W[K,NCOL] ----------------
template<int K, int NCOL, int LDO>
__global__ __launch_bounds__(256) void k_mm(const float* __restrict__ A,
    const float* __restrict__ W, float* __restrict__ out, int Mrows){
  __shared__ float wl[K*NCOL];
  __shared__ float xl[32*(K+1)];  // padded row stride: kill 16-way bank conflict
  int t = threadIdx.x;
  for (int i=t; i<K*NCOL; i+=256) wl[i] = W[i];
  int row0 = blockIdx.x*32;
  for (int i=t; i<32*K; i+=256){
    int r = i / K, c = i % K; int gr = row0 + r;
    xl[r*(K+1)+c] = (gr < Mrows) ? A[gr*K + c] : 0.f;
  }
  __syncthreads();
  int c = t & 127, rh = t >> 7;
  if (c < NCOL){
    float acc[16];
    #pragma unroll
    for (int i=0;i<16;i++) acc[i]=0.f;
    for (int k=0;k<K;k++){
      float w = wl[k*NCOL + c];
      #pragma unroll
      for (int i=0;i<16;i++) acc[i] += xl[(rh+2*i)*(K+1) + k]*w;
    }
    #pragma unroll
    for (int i=0;i<16;i++){
      int gr = row0 + rh + 2*i;
      if (gr < Mrows) out[gr*LDO + c] = acc[i];
    }
  }
}

// ---------------- per-node attention logits (4 heads x 32) ----------------
__global__ __launch_bounds__(256) void k_al(const float* __restrict__ ht,
    const float* __restrict__ a_s, const float* __restrict__ a_d,
    float* __restrict__ alS, float* __restrict__ alD, int n){
  int g = blockIdx.x*256 + threadIdx.x;
  if (g >= n*4) return;
  int node = g >> 2, h = g & 3;
  const float* row = ht + node*128 + h*32;
  float s = 0.f, dd = 0.f;
  #pragma unroll
  for (int k=0;k<32;k++){ float v = row[k]; s += v*a_s[h*32+k]; dd += v*a_d[h*32+k]; }
  alS[g] = s; alD[g] = dd;
}

// ---------------- per-node attention logits for layer 2 (1 head x 67) ----------------
__global__ __launch_bounds__(256) void k_al2(const float* __restrict__ ht2,
    const float* __restrict__ a_s, const float* __restrict__ a_d,
    float* __restrict__ alS, float* __restrict__ alD, int n){
  int g = blockIdx.x*256 + threadIdx.x;
  if (g >= n) return;
  const float* row = ht2 + g*68;
  float s = 0.f, dd = 0.f;
  #pragma unroll
  for (int k=0;k<67;k++){ float v = row[k]; s += v*a_s[k]; dd += v*a_d[k]; }
  alS[g] = s; alD[g] = dd;
}

// ---------------- per-edge softmax weights (CSR order), 4 heads ----------------
__global__ __launch_bounds__(256) void k_wexp4(const float* __restrict__ alS,
    const float* __restrict__ alD, const int* __restrict__ csr,
    const int* __restrict__ dstp, float4* __restrict__ wexp){
  int p = blockIdx.x*256 + threadIdx.x;
  if (p >= Ee) return;
  int s = csr[p], d = dstp[p];
  float4 as = *(const float4*)(alS + s*4);
  float4 ad = *(const float4*)(alD + d*4);
  float4 w;
  w.x = __expf(leaky(as.x + ad.x));
  w.y = __expf(leaky(as.y + ad.y));
  w.z = __expf(leaky(as.z + ad.z));
  w.w = __expf(leaky(as.w + ad.w));
  wexp[p] = w;
}

// ---------------- per-edge softmax weights (CSR order), 1 head ----------------
__global__ __launch_bounds__(256) void k_wexp1(const float* __restrict__ alS,
    const float* __restrict__ alD, const int* __restrict__ csr,
    const int* __restrict__ dstp, float* __restrict__ wexp){
  int p = blockIdx.x*256 + threadIdx.x;
  if (p >= Ee) return;
  int s = csr[p], d = dstp[p];
  wexp[p] = __expf(leaky(alS[s] + alD[d]));
}

// ---------------- CSR build ----------------
__global__ void k_hist(const int* __restrict__ eidx, int* __restrict__ cnt){
  int e = blockIdx.x*256 + threadIdx.x;
  if (e >= Ee) return;
  int s, d; edge_sd(e, eidx, s, d);
  atomicAdd(&cnt[d], 1);
}

// block-local exclusive scan of cnt -> row_start, block totals -> bsum
__global__ __launch_bounds__(256) void k_scan1(const int* __restrict__ cnt,
    int* __restrict__ row_start, int* __restrict__ bsum){
  __shared__ int wtot[4];
  int t = threadIdx.x, lane = t & 63, wv = t >> 6;
  int i = blockIdx.x*256 + t;
  int v = (i < NT) ? cnt[i] : 0;
  int incl = v;
  #pragma unroll
  for (int d = 1; d < 64; d <<= 1){
    int y = __shfl_up(incl, d);
    if (lane >= d) incl += y;
  }
  if (lane == 63) wtot[wv] = incl;
  __syncthreads();
  int base = 0;
  #pragma unroll
  for (int w = 0; w < 4; w++) if (w < wv) base += wtot[w];
  if (i < NT) row_start[i] = base + incl - v;
  if (t == 255) bsum[blockIdx.x] = base + incl;
}

// single-wave exclusive scan of NB block sums (NB <= 128)
__global__ __launch_bounds__(64) void k_scan2(int* __restrict__ bsum,
    int* __restrict__ row_start){
  int lane = threadIdx.x;
  int v0 = (lane < NB) ? bsum[lane] : 0;
  int v1 = (64 + lane < NB) ? bsum[64 + lane] : 0;
  int i0 = v0, i1 = v1;
  #pragma unroll
  for (int d = 1; d < 64; d <<= 1){
    int y0 = __shfl_up(i0, d), y1 = __shfl_up(i1, d);
    if (lane >= d){ i0 += y0; i1 += y1; }
  }
  int tot0 = __shfl(i0, 63);
  if (lane < NB) bsum[lane] = i0 - v0;
  if (64 + lane < NB) bsum[64 + lane] = tot0 + i1 - v1;
  if (lane == 0) row_start[NT] = Ee;
}

__global__ __launch_bounds__(256) void k_scan3(int* __restrict__ row_start,
    const int* __restrict__ bsum){
  int i = blockIdx.x*256 + threadIdx.x;
  if (i < NT) row_start[i] += bsum[blockIdx.x];
}

__global__ void k_scatter(const int* __restrict__ eidx,
    const int* __restrict__ row_start, int* __restrict__ cursor,
    int* __restrict__ csr, int* __restrict__ dstp){
  int e = blockIdx.x*256 + threadIdx.x;
  if (e >= Ee) return;
  int s, d; edge_sd(e, eidx, s, d);
  int p = row_start[d] + atomicAdd(&cursor[d], 1);
  csr[p] = s;
  dstp[p] = d;
}

// ---------------- GAT aggregation layer 0/1: agg + bias + LN + leaky ----------------
__global__ __launch_bounds__(256) void k_gat128(const float* __restrict__ ht,
    const float4* __restrict__ wexp,
    const int* __restrict__ row_start, const int* __restrict__ csr,
    const float* __restrict__ gb, const float* __restrict__ lng,
    const float* __restrict__ lnb, float* __restrict__ outH, int n){
  int wave = threadIdx.x >> 6, lane = threadIdx.x & 63;
  int d = blockIdx.x*4 + wave;
  if (d >= n) return;
  int c0 = lane, c1 = lane + 64;
  bool h0  = (c0 >> 5) != 0;   // c0 in head 1?
  bool h13 = (c1 >> 5) == 3;   // c1 in head 3?
  int begin = row_start[d], end = row_start[d+1];

  const float* __restrict__ ht0p = ht + c0;
  const float* __restrict__ ht1p = ht + c1;
  float acc0 = 0.f, acc1 = 0.f, den0 = 0.f, den1 = 0.f;
  constexpr int U = 8;
  int j = begin;
  for (; j + U <= end; j += U){
    int sidx[U];
    #pragma unroll
    for (int q=0;q<U;q++) sidx[q] = csr[j+q];
    float4 w4[U];
    #pragma unroll
    for (int q=0;q<U;q++) w4[q] = wexp[j+q];
    float hv0[U], hv1[U];
    #pragma unroll
    for (int q=0;q<U;q++){
      hv0[q] = ht0p[sidx[q]*128];
      hv1[q] = ht1p[sidx[q]*128];
    }
    #pragma unroll
    for (int q=0;q<U;q++){
      float ex0 = h0  ? w4[q].y : w4[q].x;
      float ex1 = h13 ? w4[q].w : w4[q].z;
      den0 += ex0; den1 += ex1;
      acc0 += ex0 * hv0[q]; acc1 += ex1 * hv1[q];
    }
  }
  for (; j < end; j++){
    int s = csr[j];
    float4 w = wexp[j];
    float ex0 = h0  ? w.y : w.x;
    float ex1 = h13 ? w.w : w.z;
    den0 += ex0; den1 += ex1;
    acc0 += ex0 * ht0p[s*128]; acc1 += ex1 * ht1p[s*128];
  }
  float v0 = acc0 / (den0 + 1e-16f) + gb[c0];
  float v1 = acc1 / (den1 + 1e-16f) + gb[c1];

  // LayerNorm over 128 features held by this wave (2 per lane)
  float sum = v0 + v1, sq = v0*v0 + v1*v1;
  #pragma unroll
  for (int off = 32; off; off >>= 1){
    sum += __shfl_xor(sum, off);
    sq  += __shfl_xor(sq,  off);
  }
  float mu  = sum * (1.f/128.f);
  float var = sq  * (1.f/128.f) - mu*mu;
  float inv = rsqrtf(var + 1e-5f);
  float y0 = (v0 - mu)*inv*lng[c0] + lnb[c0];
  float y1 = (v1 - mu)*inv*lng[c1] + lnb[c1];
  outH[d*128 + c0] = leaky(y0);
  outH[d*128 + c1] = leaky(y1);
}

// ---------------- GAT output layer (1 head, 67 cols) + residual + write ----------------
__global__ __launch_bounds__(256) void k_gat_out(const float* __restrict__ ht2,
    const float* __restrict__ wexp,
    const int* __restrict__ row_start, const int* __restrict__ csr,
    const float* __restrict__ gb2, const float* __restrict__ x,
    const float* __restrict__ pos, float* __restrict__ out, int n){
  int wave = threadIdx.x >> 6, lane = threadIdx.x & 63;
  int d = blockIdx.x*4 + wave;
  if (d >= n) return;
  int c0 = lane, c1 = lane + 64;
  bool has1 = (c1 < 67);
  int begin = row_start[d], end = row_start[d+1];

  const float* __restrict__ h0p = ht2 + c0;
  const float* __restrict__ h1p = ht2 + c1;
  float acc0 = 0.f, acc1 = 0.f, den = 0.f;
  constexpr int U = 8;
  int j = begin;
  for (; j + U <= end; j += U){
    int sidx[U];
    #pragma unroll
    for (int q=0;q<U;q++) sidx[q] = csr[j+q];
    float wv[U];
    #pragma unroll
    for (int q=0;q<U;q++) wv[q] = wexp[j+q];
    float hv0[U], hv1[U];
    #pragma unroll
    for (int q=0;q<U;q++){
      hv0[q] = h0p[sidx[q]*68];
      hv1[q] = has1 ? h1p[sidx[q]*68] : 0.f;
    }
    #pragma unroll
    for (int q=0;q<U;q++){
      den  += wv[q];
      acc0 += wv[q] * hv0[q];
      acc1 += wv[q] * hv1[q];
    }
  }
  for (; j < end; j++){
    int s = csr[j];
    float w = wexp[j];
    den += w;
    acc0 += w * h0p[s*68];
    if (has1) acc1 += w * h1p[s*68];
  }
  float idn = 1.f / (den + 1e-16f);
  int i = d % Nn;
  float v0 = acc0*idn + gb2[c0];
  if (c0 < 3) out[NT*64 + d*3 + c0] = pos[i*3 + c0] + v0;
  else        out[d*64 + (c0-3)]    = x[i*64 + (c0-3)] + v0;
  if (has1){
    float v1 = acc1*idn + gb2[c1];
    out[d*64 + (c1-3)] = x[i*64 + (c1-3)] + v1;
  }
}

extern "C" void kernel_launch(void* const* d_in, const int* in_sizes, int n_in,
                              void* d_out, int out_size, void* d_ws, size_t ws_size,
                              hipStream_t stream){
  const float* z    = (const float*)d_in[0];
  const float* x    = (const float*)d_in[1];
  const float* pos  = (const float*)d_in[2];
  const int*   eidx = (const int*)  d_in[3];
  const float* w1   = (const float*)d_in[4];
  const float* b1   = (const float*)d_in[5];
  const float* w2   = (const float*)d_in[6];
  const float* b2   = (const float*)d_in[7];
  const float* w3   = (const float*)d_in[8];
  const float* b3   = (const float*)d_in[9];
  const float* gw0  = (const float*)d_in[10];
  const float* ga0s = (const float*)d_in[11];
  const float* ga0d = (const float*)d_in[12];
  const float* gb0  = (const float*)d_in[13];
  const float* gw1  = (const float*)d_in[14];
  const float* ga1s = (const float*)d_in[15];
  const float* ga1d = (const float*)d_in[16];
  const float* gb1  = (const float*)d_in[17];
  const float* gw2  = (const float*)d_in[18];
  const float* ga2s = (const float*)d_in[19];
  const float* ga2d = (const float*)d_in[20];
  const float* gb2  = (const float*)d_in[21];
  const float* ln0g = (const float*)d_in[22];
  const float* ln0b = (const float*)d_in[23];
  const float* ln1g = (const float*)d_in[24];
  const float* ln1b = (const float*)d_in[25];
  float* out = (float*)d_out;

  float* ws       = (float*)d_ws;
  float* styleW0  = ws;                  // 256
  float* alS      = ws + 256;            // 80000
  float* alD      = alS + 80000;         // 80000
  float* bufA     = alD + 80000;         // NT*128
  float* bufB     = bufA + NT*128;       // NT*128
  float* wexp     = bufB + NT*128;       // Ee*4 (layer2 reuses as Ee*1)
  int*   cnt      = (int*)(wexp + (size_t)Ee*4);  // NT
  int*   cursor   = cnt + NT;                // NT
  int*   bsum     = cursor + NT;             // 128
  int*   row_start= bsum + 128;              // NT+1
  int*   csr      = row_start + NT + 1;      // Ee
  int*   dstp     = csr + Ee;                // Ee

  // style path
  k_style<<<1, 512, 0, stream>>>(z, w1, b1, w2, b2, w3, b3, gw0, styleW0);

  // CSR by dst
  hipMemsetAsync(cnt, 0, 2*NT*sizeof(int), stream);   // cnt + cursor
  k_hist<<<(Ee+255)/256, 256, 0, stream>>>(eidx, cnt);
  k_scan1<<<NB, 256, 0, stream>>>(cnt, row_start, bsum);
  k_scan2<<<1, 64, 0, stream>>>(bsum, row_start);
  k_scan3<<<NB, 256, 0, stream>>>(row_start, bsum);
  k_scatter<<<(Ee+255)/256, 256, 0, stream>>>(eidx, row_start, cursor, csr, dstp);

  const int EB = (Ee+255)/256;
  // layer 0
  k_ht0<<<(Nn+31)/32, 256, 0, stream>>>(x, gw0, styleW0, bufA);
  k_al<<<(NT*4+255)/256, 256, 0, stream>>>(bufA, ga0s, ga0d, alS, alD, NT);
  k_wexp4<<<EB, 256, 0, stream>>>(alS, alD, csr, dstp, (float4*)wexp);
  k_gat128<<<(NT+3)/4, 256, 0, stream>>>(bufA, (const float4*)wexp, row_start, csr,
                                         gb0, ln0g, ln0b, bufB, NT);
  // layer 1
  k_mm<128,128,128><<<(NT+31)/32, 256, 0, stream>>>(bufB, gw1, bufA, NT);
  k_al<<<(NT*4+255)/256, 256, 0, stream>>>(bufA, ga1s, ga1d, alS, alD, NT);
  k_wexp4<<<EB, 256, 0, stream>>>(alS, alD, csr, dstp, (float4*)wexp);
  k_gat128<<<(NT+3)/4, 256, 0, stream>>>(bufA, (const float4*)wexp, row_start, csr,
                                         gb1, ln1g, ln1b, bufB, NT);
  // layer 2 (1 head, 67 outputs, fused residual + final write)
  k_mm<128,67,68><<<(NT+31)/32, 256, 0, stream>>>(bufB, gw2, bufA, NT);
  k_al2<<<(NT+255)/256, 256, 0, stream>>>(bufA, ga2s, ga2d, alS, alD, NT);
  k_wexp1<<<EB, 256, 0, stream>>>(alS, alD, csr, dstp, wexp);
  k_gat_out<<<(NT+3)/4, 256, 0, stream>>>(bufA, wexp, row_start, csr,
                                          gb2, x, pos, out, NT);
}

// Round 4
// 312.431 us; speedup vs baseline: 1.2318x; 1.2318x over previous
//
#include <hip/hip_runtime.h>
#include <hip/hip_bf16.h>

#define DEV_INLINE __device__ __forceinline__

constexpr int Nn   = 10000;     // nodes per batch
constexpr int NT   = 20000;     // B*N
constexpr int Me   = 320000;    // template edges
constexpr int Ee   = 2*Me + NT; // 660000 total edges
constexpr int NB   = (NT + 255) / 256;  // scan blocks = 79
constexpr float NEG = 0.2f;

typedef float  f32x4  __attribute__((ext_vector_type(4)));
typedef short  bf16x8 __attribute__((ext_vector_type(8)));

DEV_INLINE float leaky(float x){ return x >= 0.f ? x : NEG*x; }

DEV_INLINE ushort f2bf(float v){
  __hip_bfloat16 h = __float2bfloat16(v);
  return *reinterpret_cast<ushort*>(&h);
}

DEV_INLINE void edge_sd(int e, const int* __restrict__ eidx, int& s, int& d){
  if (e < 2*Me){
    int b = (e >= Me) ? 1 : 0;
    int t = e - b*Me;
    s = eidx[t]      + b*Nn;
    d = eidx[Me + t] + b*Nn;
  } else {
    s = e - 2*Me; d = s;
  }
}

// ---------------- style MLP + style @ gw0[64:,:] ----------------
__global__ __launch_bounds__(512) void k_style(const float* __restrict__ z,
    const float* __restrict__ w1, const float* __restrict__ b1,
    const float* __restrict__ w2, const float* __restrict__ b2,
    const float* __restrict__ w3, const float* __restrict__ b3,
    const float* __restrict__ gw0, float* __restrict__ styleW0){
  __shared__ float zl[2][128];
  __shared__ float s1[2][256];
  __shared__ float s2[2][512];
  __shared__ float st[2][128];
  int t = threadIdx.x;
  if (t < 256) zl[t>>7][t&127] = z[t];
  __syncthreads();
  { int b = t>>8, j = t&255; float acc = b1[j];
    for (int k=0;k<128;k++) acc += zl[b][k]*w1[k*256+j];
    s1[b][j] = leaky(acc); }
  __syncthreads();
  { int j = t;
    for (int b=0;b<2;b++){ float acc = b2[j];
      for (int k=0;k<256;k++) acc += s1[b][k]*w2[k*512+j];
      s2[b][j] = leaky(acc); } }
  __syncthreads();
  if (t < 256){ int b=t>>7, j=t&127; float acc=b3[j];
    for (int k=0;k<512;k++) acc += s2[b][k]*w3[k*128+j];
    st[b][j] = acc; }
  __syncthreads();
  if (t < 256){ int b=t>>7, j=t&127; float acc=0.f;
    for (int k=0;k<128;k++) acc += st[b][k]*gw0[(64+k)*128 + j];
    styleW0[b*128+j] = acc; }
}

// ---------------- ht0 = x @ gw0[:64,:] + styleW0[b]  (both batches) ----------------
__global__ __launch_bounds__(256) void k_ht0(const float* __restrict__ x,
    const float* __restrict__ gw0, const float* __restrict__ styleW0,
    float* __restrict__ ht0){
  __shared__ float wl[64][128];
  __shared__ float xl[32][64];
  __shared__ float sw[2][128];
  int t = threadIdx.x;
  for (int i=t; i<64*128; i+=256) wl[i>>7][i&127] = gw0[i];
  if (t < 256) sw[t>>7][t&127] = styleW0[t];
  int row0 = blockIdx.x*32;
  for (int i=t; i<32*64; i+=256){
    int r = i>>6, c = i&63; int gr = row0 + r;
    xl[r][c] = (gr < Nn) ? x[gr*64 + c] : 0.f;
  }
  __syncthreads();
  int c = t & 127, rh = t >> 7;
  float acc[16];
  #pragma unroll
  for (int i=0;i<16;i++) acc[i]=0.f;
  for (int k=0;k<64;k++){
    float w = wl[k][c];
    #pragma unroll
    for (int i=0;i<16;i++) acc[i] += xl[rh+2*i][k]*w;
  }
  float s0 = sw[0][c], s1 = sw[1][c];
  #pragma unroll
  for (int i=0;i<16;i++){
    int gr = row0 + rh + 2*i;
    if (gr < Nn){
      ht0[gr*128 + c]        = acc[i] + s0;
      ht0[(Nn+gr)*128 + c]   = acc[i] + s1;
    }
  }
}

// ---------------- MFMA matmul: out[M,LDO](f32) = A[M,128](bf16) @ W[128,NCOL](f32) ----------------
// 256 thr = 4 waves; block tile 128 rows; per-wave 32 rows (2 m-frags), NF n-frags.
template<int NCOL, int LDO, int NF>
__global__ __launch_bounds__(256) void k_mm_mfma(const ushort* __restrict__ A,
    const float* __restrict__ W, float* __restrict__ out, int M){
  constexpr int NCOLP = NF*16;
  __shared__ ushort bt[NCOLP*128];  // Bt[c][k], XOR-swizzled
  int t = threadIdx.x;
  int wid = t >> 6, lane = t & 63, l15 = lane & 15, g = lane >> 4;
  int mbase = blockIdx.x*128 + wid*32;

  // issue A-fragment loads early (direct global->reg, bf16 already)
  bf16x8 afr[2][4];
  #pragma unroll
  for (int mf=0; mf<2; mf++){
    int row = mbase + mf*16 + l15;
    int rc = row < M ? row : M-1;
    const ushort* ap = A + (size_t)rc*128 + g*8;
    #pragma unroll
    for (int ks=0; ks<4; ks++)
      afr[mf][ks] = *(const bf16x8*)(ap + ks*32);
  }

  // stage W -> LDS transposed bf16 with XOR swizzle (byte ^= (c&7)<<4)
  for (int idx = t; idx < 128*NCOLP; idx += 256){
    int k = idx / NCOLP, c = idx % NCOLP;
    float v = (c < NCOL) ? W[k*NCOL + c] : 0.f;
    uint byte = ((uint)(c*128 + k) << 1) ^ ((uint)(c&7) << 4);
    *(ushort*)((char*)bt + byte) = f2bf(v);
  }
  __syncthreads();

  f32x4 acc[2][NF];
  #pragma unroll
  for (int mf=0; mf<2; mf++)
    #pragma unroll
    for (int nf=0; nf<NF; nf++) acc[mf][nf] = (f32x4){0.f,0.f,0.f,0.f};

  #pragma unroll
  for (int ks=0; ks<4; ks++){
    int kb = ks*32 + g*8;
    bf16x8 bfr[NF];
    #pragma unroll
    for (int nf=0; nf<NF; nf++){
      int c = nf*16 + l15;
      uint byte = ((uint)(c*128 + kb) << 1) ^ ((uint)(c&7) << 4);
      bfr[nf] = *(const bf16x8*)((const char*)bt + byte);
    }
    #pragma unroll
    for (int mf=0; mf<2; mf++)
      #pragma unroll
      for (int nf=0; nf<NF; nf++)
        acc[mf][nf] = __builtin_amdgcn_mfma_f32_16x16x32_bf16(
            afr[mf][ks], bfr[nf], acc[mf][nf], 0, 0, 0);
  }

  // C/D layout: col = lane&15, row = (lane>>4)*4 + r   [m89-verified]
  #pragma unroll
  for (int mf=0; mf<2; mf++){
    int rbase = mbase + mf*16 + g*4;
    #pragma unroll
    for (int nf=0; nf<NF; nf++){
      int c = nf*16 + l15;
      if (c < NCOL){
        #pragma unroll
        for (int r=0; r<4; r++){
          int row = rbase + r;
          if (row < M) out[(size_t)row*LDO + c] = acc[mf][nf][r];
        }
      }
    }
  }
}

// ---------------- per-node attention logits (4 heads x 32) ----------------
__global__ __launch_bounds__(256) void k_al(const float* __restrict__ ht,
    const float* __restrict__ a_s, const float* __restrict__ a_d,
    float* __restrict__ alS, float* __restrict__ alD, int n){
  int g = blockIdx.x*256 + threadIdx.x;
  if (g >= n*4) return;
  int node = g >> 2, h = g & 3;
  const float* row = ht + node*128 + h*32;
  float s = 0.f, dd = 0.f;
  #pragma unroll
  for (int k=0;k<32;k++){ float v = row[k]; s += v*a_s[h*32+k]; dd += v*a_d[h*32+k]; }
  alS[g] = s; alD[g] = dd;
}

// ---------------- per-node attention logits for layer 2 (1 head x 67) ----------------
__global__ __launch_bounds__(256) void k_al2(const float* __restrict__ ht2,
    const float* __restrict__ a_s, const float* __restrict__ a_d,
    float* __restrict__ alS, float* __restrict__ alD, int n){
  int g = blockIdx.x*256 + threadIdx.x;
  if (g >= n) return;
  const float* row = ht2 + g*68;
  float s = 0.f, dd = 0.f;
  #pragma unroll
  for (int k=0;k<67;k++){ float v = row[k]; s += v*a_s[k]; dd += v*a_d[k]; }
  alS[g] = s; alD[g] = dd;
}

// ---------------- per-edge softmax weights (CSR order), 4 heads ----------------
__global__ __launch_bounds__(256) void k_wexp4(const float* __restrict__ alS,
    const float* __restrict__ alD, const int* __restrict__ csr,
    const int* __restrict__ dstp, float4* __restrict__ wexp){
  int p = blockIdx.x*256 + threadIdx.x;
  if (p >= Ee) return;
  int s = csr[p], d = dstp[p];
  float4 as = *(const float4*)(alS + s*4);
  float4 ad = *(const float4*)(alD + d*4);
  float4 w;
  w.x = __expf(leaky(as.x + ad.x));
  w.y = __expf(leaky(as.y + ad.y));
  w.z = __expf(leaky(as.z + ad.z));
  w.w = __expf(leaky(as.w + ad.w));
  wexp[p] = w;
}

// ---------------- per-edge softmax weights (CSR order), 1 head ----------------
__global__ __launch_bounds__(256) void k_wexp1(const float* __restrict__ alS,
    const float* __restrict__ alD, const int* __restrict__ csr,
    const int* __restrict__ dstp, float* __restrict__ wexp){
  int p = blockIdx.x*256 + threadIdx.x;
  if (p >= Ee) return;
  int s = csr[p], d = dstp[p];
  wexp[p] = __expf(leaky(alS[s] + alD[d]));
}

// ---------------- CSR build ----------------
__global__ void k_hist(const int* __restrict__ eidx, int* __restrict__ cnt){
  int e = blockIdx.x*256 + threadIdx.x;
  if (e >= Ee) return;
  int s, d; edge_sd(e, eidx, s, d);
  atomicAdd(&cnt[d], 1);
}

// block-local exclusive scan of cnt -> row_start, block totals -> bsum
__global__ __launch_bounds__(256) void k_scan1(const int* __restrict__ cnt,
    int* __restrict__ row_start, int* __restrict__ bsum){
  __shared__ int wtot[4];
  int t = threadIdx.x, lane = t & 63, wv = t >> 6;
  int i = blockIdx.x*256 + t;
  int v = (i < NT) ? cnt[i] : 0;
  int incl = v;
  #pragma unroll
  for (int d = 1; d < 64; d <<= 1){
    int y = __shfl_up(incl, d);
    if (lane >= d) incl += y;
  }
  if (lane == 63) wtot[wv] = incl;
  __syncthreads();
  int base = 0;
  #pragma unroll
  for (int w = 0; w < 4; w++) if (w < wv) base += wtot[w];
  if (i < NT) row_start[i] = base + incl - v;
  if (t == 255) bsum[blockIdx.x] = base + incl;
}

// single-wave exclusive scan of NB block sums (NB <= 128)
__global__ __launch_bounds__(64) void k_scan2(int* __restrict__ bsum,
    int* __restrict__ row_start){
  int lane = threadIdx.x;
  int v0 = (lane < NB) ? bsum[lane] : 0;
  int v1 = (64 + lane < NB) ? bsum[64 + lane] : 0;
  int i0 = v0, i1 = v1;
  #pragma unroll
  for (int d = 1; d < 64; d <<= 1){
    int y0 = __shfl_up(i0, d), y1 = __shfl_up(i1, d);
    if (lane >= d){ i0 += y0; i1 += y1; }
  }
  int tot0 = __shfl(i0, 63);
  if (lane < NB) bsum[lane] = i0 - v0;
  if (64 + lane < NB) bsum[64 + lane] = tot0 + i1 - v1;
  if (lane == 0) row_start[NT] = Ee;
}

__global__ __launch_bounds__(256) void k_scan3(int* __restrict__ row_start,
    const int* __restrict__ bsum){
  int i = blockIdx.x*256 + threadIdx.x;
  if (i < NT) row_start[i] += bsum[blockIdx.x];
}

__global__ void k_scatter(const int* __restrict__ eidx,
    const int* __restrict__ row_start, int* __restrict__ cursor,
    int* __restrict__ csr, int* __restrict__ dstp){
  int e = blockIdx.x*256 + threadIdx.x;
  if (e >= Ee) return;
  int s, d; edge_sd(e, eidx, s, d);
  int p = row_start[d] + atomicAdd(&cursor[d], 1);
  csr[p] = s;
  dstp[p] = d;
}

// ---------------- GAT aggregation layer 0/1: agg + bias + LN + leaky -> bf16 ----------------
__global__ __launch_bounds__(256) void k_gat128(const float* __restrict__ ht,
    const float4* __restrict__ wexp,
    const int* __restrict__ row_start, const int* __restrict__ csr,
    const float* __restrict__ gb, const float* __restrict__ lng,
    const float* __restrict__ lnb, __hip_bfloat16* __restrict__ outH, int n){
  int wave = threadIdx.x >> 6, lane = threadIdx.x & 63;
  int d = blockIdx.x*4 + wave;
  if (d >= n) return;
  int c0 = lane, c1 = lane + 64;
  bool h0  = (c0 >> 5) != 0;   // c0 in head 1?
  bool h13 = (c1 >> 5) == 3;   // c1 in head 3?
  int begin = row_start[d], end = row_start[d+1];

  const float* __restrict__ ht0p = ht + c0;
  const float* __restrict__ ht1p = ht + c1;
  float acc0 = 0.f, acc1 = 0.f, den0 = 0.f, den1 = 0.f;
  constexpr int U = 8;
  int j = begin;
  for (; j + U <= end; j += U){
    int sidx[U];
    #pragma unroll
    for (int q=0;q<U;q++) sidx[q] = csr[j+q];
    float4 w4[U];
    #pragma unroll
    for (int q=0;q<U;q++) w4[q] = wexp[j+q];
    float hv0[U], hv1[U];
    #pragma unroll
    for (int q=0;q<U;q++){
      hv0[q] = ht0p[sidx[q]*128];
      hv1[q] = ht1p[sidx[q]*128];
    }
    #pragma unroll
    for (int q=0;q<U;q++){
      float ex0 = h0  ? w4[q].y : w4[q].x;
      float ex1 = h13 ? w4[q].w : w4[q].z;
      den0 += ex0; den1 += ex1;
      acc0 += ex0 * hv0[q]; acc1 += ex1 * hv1[q];
    }
  }
  for (; j < end; j++){
    int s = csr[j];
    float4 w = wexp[j];
    float ex0 = h0  ? w.y : w.x;
    float ex1 = h13 ? w.w : w.z;
    den0 += ex0; den1 += ex1;
    acc0 += ex0 * ht0p[s*128]; acc1 += ex1 * ht1p[s*128];
  }
  float v0 = acc0 / (den0 + 1e-16f) + gb[c0];
  float v1 = acc1 / (den1 + 1e-16f) + gb[c1];

  // LayerNorm over 128 features held by this wave (2 per lane)
  float sum = v0 + v1, sq = v0*v0 + v1*v1;
  #pragma unroll
  for (int off = 32; off; off >>= 1){
    sum += __shfl_xor(sum, off);
    sq  += __shfl_xor(sq,  off);
  }
  float mu  = sum * (1.f/128.f);
  float var = sq  * (1.f/128.f) - mu*mu;
  float inv = rsqrtf(var + 1e-5f);
  float y0 = (v0 - mu)*inv*lng[c0] + lnb[c0];
  float y1 = (v1 - mu)*inv*lng[c1] + lnb[c1];
  outH[d*128 + c0] = __float2bfloat16(leaky(y0));
  outH[d*128 + c1] = __float2bfloat16(leaky(y1));
}

// ---------------- GAT output layer (1 head, 67 cols) + residual + write ----------------
__global__ __launch_bounds__(256) void k_gat_out(const float* __restrict__ ht2,
    const float* __restrict__ wexp,
    const int* __restrict__ row_start, const int* __restrict__ csr,
    const float* __restrict__ gb2, const float* __restrict__ x,
    const float* __restrict__ pos, float* __restrict__ out, int n){
  int wave = threadIdx.x >> 6, lane = threadIdx.x & 63;
  int d = blockIdx.x*4 + wave;
  if (d >= n) return;
  int c0 = lane, c1 = lane + 64;
  bool has1 = (c1 < 67);
  int begin = row_start[d], end = row_start[d+1];

  const float* __restrict__ h0p = ht2 + c0;
  const float* __restrict__ h1p = ht2 + c1;
  float acc0 = 0.f, acc1 = 0.f, den = 0.f;
  constexpr int U = 8;
  int j = begin;
  for (; j + U <= end; j += U){
    int sidx[U];
    #pragma unroll
    for (int q=0;q<U;q++) sidx[q] = csr[j+q];
    float wv[U];
    #pragma unroll
    for (int q=0;q<U;q++) wv[q] = wexp[j+q];
    float hv0[U], hv1[U];
    #pragma unroll
    for (int q=0;q<U;q++){
      hv0[q] = h0p[sidx[q]*68];
      hv1[q] = has1 ? h1p[sidx[q]*68] : 0.f;
    }
    #pragma unroll
    for (int q=0;q<U;q++){
      den  += wv[q];
      acc0 += wv[q] * hv0[q];
      acc1 += wv[q] * hv1[q];
    }
  }
  for (; j < end; j++){
    int s = csr[j];
    float w = wexp[j];
    den += w;
    acc0 += w * h0p[s*68];
    if (has1) acc1 += w * h1p[s*68];
  }
  float idn = 1.f / (den + 1e-16f);
  int i = d % Nn;
  float v0 = acc0*idn + gb2[c0];
  if (c0 < 3) out[NT*64 + d*3 + c0] = pos[i*3 + c0] + v0;
  else        out[d*64 + (c0-3)]    = x[i*64 + (c0-3)] + v0;
  if (has1){
    float v1 = acc1*idn + gb2[c1];
    out[d*64 + (c1-3)] = x[i*64 + (c1-3)] + v1;
  }
}

extern "C" void kernel_launch(void* const* d_in, const int* in_sizes, int n_in,
                              void* d_out, int out_size, void* d_ws, size_t ws_size,
                              hipStream_t stream){
  const float* z    = (const float*)d_in[0];
  const float* x    = (const float*)d_in[1];
  const float* pos  = (const float*)d_in[2];
  const int*   eidx = (const int*)  d_in[3];
  const float* w1   = (const float*)d_in[4];
  const float* b1   = (const float*)d_in[5];
  const float* w2   = (const float*)d_in[6];
  const float* b2   = (const float*)d_in[7];
  const float* w3   = (const float*)d_in[8];
  const float* b3   = (const float*)d_in[9];
  const float* gw0  = (const float*)d_in[10];
  const float* ga0s = (const float*)d_in[11];
  const float* ga0d = (const float*)d_in[12];
  const float* gb0  = (const float*)d_in[13];
  const float* gw1  = (const float*)d_in[14];
  const float* ga1s = (const float*)d_in[15];
  const float* ga1d = (const float*)d_in[16];
  const float* gb1  = (const float*)d_in[17];
  const float* gw2  = (const float*)d_in[18];
  const float* ga2s = (const float*)d_in[19];
  const float* ga2d = (const float*)d_in[20];
  const float* gb2  = (const float*)d_in[21];
  const float* ln0g = (const float*)d_in[22];
  const float* ln0b = (const float*)d_in[23];
  const float* ln1g = (const float*)d_in[24];
  const float* ln1b = (const float*)d_in[25];
  float* out = (float*)d_out;

  float* ws       = (float*)d_ws;
  float* styleW0  = ws;                  // 256
  float* alS      = ws + 256;            // 80000
  float* alD      = alS + 80000;         // 80000
  float* bufA     = alD + 80000;         // NT*128 f32
  __hip_bfloat16* bufB = (__hip_bfloat16*)(bufA + NT*128);  // NT*128 bf16 (uses f32-sized slot)
  float* wexp     = bufA + 2*NT*128;     // Ee*4 (layer2 reuses as Ee*1)
  int*   cnt      = (int*)(wexp + (size_t)Ee*4);  // NT
  int*   cursor   = cnt + NT;                // NT
  int*   bsum     = cursor + NT;             // 128
  int*   row_start= bsum + 128;              // NT+1
  int*   csr      = row_start + NT + 1;      // Ee
  int*   dstp     = csr + Ee;                // Ee

  // style path
  k_style<<<1, 512, 0, stream>>>(z, w1, b1, w2, b2, w3, b3, gw0, styleW0);

  // CSR by dst
  hipMemsetAsync(cnt, 0, 2*NT*sizeof(int), stream);   // cnt + cursor
  k_hist<<<(Ee+255)/256, 256, 0, stream>>>(eidx, cnt);
  k_scan1<<<NB, 256, 0, stream>>>(cnt, row_start, bsum);
  k_scan2<<<1, 64, 0, stream>>>(bsum, row_start);
  k_scan3<<<NB, 256, 0, stream>>>(row_start, bsum);
  k_scatter<<<(Ee+255)/256, 256, 0, stream>>>(eidx, row_start, cursor, csr, dstp);

  const int EB = (Ee+255)/256;
  const int MB = (NT+127)/128;
  // layer 0
  k_ht0<<<(Nn+31)/32, 256, 0, stream>>>(x, gw0, styleW0, bufA);
  k_al<<<(NT*4+255)/256, 256, 0, stream>>>(bufA, ga0s, ga0d, alS, alD, NT);
  k_wexp4<<<EB, 256, 0, stream>>>(alS, alD, csr, dstp, (float4*)wexp);
  k_gat128<<<(NT+3)/4, 256, 0, stream>>>(bufA, (const float4*)wexp, row_start, csr,
                                         gb0, ln0g, ln0b, bufB, NT);
  // layer 1
  k_mm_mfma<128,128,8><<<MB, 256, 0, stream>>>((const ushort*)bufB, gw1, bufA, NT);
  k_al<<<(NT*4+255)/256, 256, 0, stream>>>(bufA, ga1s, ga1d, alS, alD, NT);
  k_wexp4<<<EB, 256, 0, stream>>>(alS, alD, csr, dstp, (float4*)wexp);
  k_gat128<<<(NT+3)/4, 256, 0, stream>>>(bufA, (const float4*)wexp, row_start, csr,
                                         gb1, ln1g, ln1b, bufB, NT);
  // layer 2 (1 head, 67 outputs, fused residual + final write)
  k_mm_mfma<67,68,5><<<MB, 256, 0, stream>>>((const ushort*)bufB, gw2, bufA, NT);
  k_al2<<<(NT+255)/256, 256, 0, stream>>>(bufA, ga2s, ga2d, alS, alD, NT);
  k_wexp1<<<EB, 256, 0, stream>>>(alS, alD, csr, dstp, wexp);
  k_gat_out<<<(NT+3)/4, 256, 0, stream>>>(bufA, wexp, row_start, csr,
                                          gb2, x, pos, out, NT);
}

// Round 5
// 228.437 us; speedup vs baseline: 1.6847x; 1.3677x over previous
//
#include <hip/hip_runtime.h>
#include <hip/hip_bf16.h>

#define DEV_INLINE __device__ __forceinline__

constexpr int Nn   = 10000;     // nodes per batch
constexpr int NT   = 20000;     // B*N
constexpr int Me   = 320000;    // template edges
constexpr int NB2  = (Nn + 255) / 256;  // scan blocks over template nodes = 40
constexpr float NEG = 0.2f;

typedef float  f32x4  __attribute__((ext_vector_type(4)));
typedef short  bf16x8 __attribute__((ext_vector_type(8)));

DEV_INLINE float leaky(float x){ return x >= 0.f ? x : NEG*x; }

DEV_INLINE ushort f2bf(float v){
  __hip_bfloat16 h = __float2bfloat16(v);
  return *reinterpret_cast<ushort*>(&h);
}

// ---------------- style MLP + style @ gw0[64:,:] ----------------
__global__ __launch_bounds__(512) void k_style(const float* __restrict__ z,
    const float* __restrict__ w1, const float* __restrict__ b1,
    const float* __restrict__ w2, const float* __restrict__ b2,
    const float* __restrict__ w3, const float* __restrict__ b3,
    const float* __restrict__ gw0, float* __restrict__ styleW0){
  __shared__ float zl[2][128];
  __shared__ float s1[2][256];
  __shared__ float s2[2][512];
  __shared__ float st[2][128];
  int t = threadIdx.x;
  if (t < 256) zl[t>>7][t&127] = z[t];
  __syncthreads();
  { int b = t>>8, j = t&255; float acc = b1[j];
    for (int k=0;k<128;k++) acc += zl[b][k]*w1[k*256+j];
    s1[b][j] = leaky(acc); }
  __syncthreads();
  { int j = t;
    for (int b=0;b<2;b++){ float acc = b2[j];
      for (int k=0;k<256;k++) acc += s1[b][k]*w2[k*512+j];
      s2[b][j] = leaky(acc); } }
  __syncthreads();
  if (t < 256){ int b=t>>7, j=t&127; float acc=b3[j];
    for (int k=0;k<512;k++) acc += s2[b][k]*w3[k*128+j];
    st[b][j] = acc; }
  __syncthreads();
  if (t < 256){ int b=t>>7, j=t&127; float acc=0.f;
    for (int k=0;k<128;k++) acc += st[b][k]*gw0[(64+k)*128 + j];
    styleW0[b*128+j] = acc; }
}

// ---------------- ht0 = x @ gw0[:64,:] + styleW0[b]  (both batches) ----------------
__global__ __launch_bounds__(256) void k_ht0(const float* __restrict__ x,
    const float* __restrict__ gw0, const float* __restrict__ styleW0,
    float* __restrict__ ht0){
  __shared__ float wl[64][128];
  __shared__ float xl[32][64];
  __shared__ float sw[2][128];
  int t = threadIdx.x;
  for (int i=t; i<64*128; i+=256) wl[i>>7][i&127] = gw0[i];
  if (t < 256) sw[t>>7][t&127] = styleW0[t];
  int row0 = blockIdx.x*32;
  for (int i=t; i<32*64; i+=256){
    int r = i>>6, c = i&63; int gr = row0 + r;
    xl[r][c] = (gr < Nn) ? x[gr*64 + c] : 0.f;
  }
  __syncthreads();
  int c = t & 127, rh = t >> 7;
  float acc[16];
  #pragma unroll
  for (int i=0;i<16;i++) acc[i]=0.f;
  for (int k=0;k<64;k++){
    float w = wl[k][c];
    #pragma unroll
    for (int i=0;i<16;i++) acc[i] += xl[rh+2*i][k]*w;
  }
  float s0 = sw[0][c], s1 = sw[1][c];
  #pragma unroll
  for (int i=0;i<16;i++){
    int gr = row0 + rh + 2*i;
    if (gr < Nn){
      ht0[gr*128 + c]        = acc[i] + s0;
      ht0[(Nn+gr)*128 + c]   = acc[i] + s1;
    }
  }
}

// ---------------- MFMA matmul: out[M,LDO](f32) = A[M,128](bf16) @ W[128,NCOL](f32) ----------------
template<int NCOL, int LDO, int NF>
__global__ __launch_bounds__(256) void k_mm_mfma(const ushort* __restrict__ A,
    const float* __restrict__ W, float* __restrict__ out, int M){
  constexpr int NCOLP = NF*16;
  __shared__ ushort bt[NCOLP*128];  // Bt[c][k], XOR-swizzled
  int t = threadIdx.x;
  int wid = t >> 6, lane = t & 63, l15 = lane & 15, g = lane >> 4;
  int mbase = blockIdx.x*128 + wid*32;

  // issue A-fragment loads early (direct global->reg, bf16 already)
  bf16x8 afr[2][4];
  #pragma unroll
  for (int mf=0; mf<2; mf++){
    int row = mbase + mf*16 + l15;
    int rc = row < M ? row : M-1;
    const ushort* ap = A + (size_t)rc*128 + g*8;
    #pragma unroll
    for (int ks=0; ks<4; ks++)
      afr[mf][ks] = *(const bf16x8*)(ap + ks*32);
  }

  // stage W -> LDS transposed bf16 with XOR swizzle (byte ^= (c&7)<<4)
  for (int idx = t; idx < 128*NCOLP; idx += 256){
    int k = idx / NCOLP, c = idx % NCOLP;
    float v = (c < NCOL) ? W[k*NCOL + c] : 0.f;
    uint byte = ((uint)(c*128 + k) << 1) ^ ((uint)(c&7) << 4);
    *(ushort*)((char*)bt + byte) = f2bf(v);
  }
  __syncthreads();

  f32x4 acc[2][NF];
  #pragma unroll
  for (int mf=0; mf<2; mf++)
    #pragma unroll
    for (int nf=0; nf<NF; nf++) acc[mf][nf] = (f32x4){0.f,0.f,0.f,0.f};

  #pragma unroll
  for (int ks=0; ks<4; ks++){
    int kb = ks*32 + g*8;
    bf16x8 bfr[NF];
    #pragma unroll
    for (int nf=0; nf<NF; nf++){
      int c = nf*16 + l15;
      uint byte = ((uint)(c*128 + kb) << 1) ^ ((uint)(c&7) << 4);
      bfr[nf] = *(const bf16x8*)((const char*)bt + byte);
    }
    #pragma unroll
    for (int mf=0; mf<2; mf++)
      #pragma unroll
      for (int nf=0; nf<NF; nf++)
        acc[mf][nf] = __builtin_amdgcn_mfma_f32_16x16x32_bf16(
            afr[mf][ks], bfr[nf], acc[mf][nf], 0, 0, 0);
  }

  // C/D layout: col = lane&15, row = (lane>>4)*4 + r   [m89-verified]
  #pragma unroll
  for (int mf=0; mf<2; mf++){
    int rbase = mbase + mf*16 + g*4;
    #pragma unroll
    for (int nf=0; nf<NF; nf++){
      int c = nf*16 + l15;
      if (c < NCOL){
        #pragma unroll
        for (int r=0; r<4; r++){
          int row = rbase + r;
          if (row < M) out[(size_t)row*LDO + c] = acc[mf][nf][r];
        }
      }
    }
  }
}

// ---------------- per-node attention logits (4 heads x 32) ----------------
__global__ __launch_bounds__(256) void k_al(const float* __restrict__ ht,
    const float* __restrict__ a_s, const float* __restrict__ a_d,
    float* __restrict__ alS, float* __restrict__ alD, int n){
  int g = blockIdx.x*256 + threadIdx.x;
  if (g >= n*4) return;
  int node = g >> 2, h = g & 3;
  const float* row = ht + node*128 + h*32;
  float s = 0.f, dd = 0.f;
  #pragma unroll
  for (int k=0;k<32;k++){ float v = row[k]; s += v*a_s[h*32+k]; dd += v*a_d[h*32+k]; }
  alS[g] = s; alD[g] = dd;
}

// ---------------- per-node attention logits for layer 2 (1 head x 67) ----------------
__global__ __launch_bounds__(256) void k_al2(const float* __restrict__ ht2,
    const float* __restrict__ a_s, const float* __restrict__ a_d,
    float* __restrict__ alS, float* __restrict__ alD, int n){
  int g = blockIdx.x*256 + threadIdx.x;
  if (g >= n) return;
  const float* row = ht2 + g*68;
  float s = 0.f, dd = 0.f;
  #pragma unroll
  for (int k=0;k<67;k++){ float v = row[k]; s += v*a_s[k]; dd += v*a_d[k]; }
  alS[g] = s; alD[g] = dd;
}

// ---------------- CSR build (TEMPLATE graph only: Me edges, Nn nodes) ----------------
__global__ void k_hist(const int* __restrict__ eidx, int* __restrict__ cnt){
  int e = blockIdx.x*256 + threadIdx.x;
  if (e >= Me) return;
  atomicAdd(&cnt[eidx[Me + e]], 1);
}

// block-local exclusive scan of cnt -> row_start, block totals -> bsum
__global__ __launch_bounds__(256) void k_scan1(const int* __restrict__ cnt,
    int* __restrict__ row_start, int* __restrict__ bsum){
  __shared__ int wtot[4];
  int t = threadIdx.x, lane = t & 63, wv = t >> 6;
  int i = blockIdx.x*256 + t;
  int v = (i < Nn) ? cnt[i] : 0;
  int incl = v;
  #pragma unroll
  for (int d = 1; d < 64; d <<= 1){
    int y = __shfl_up(incl, d);
    if (lane >= d) incl += y;
  }
  if (lane == 63) wtot[wv] = incl;
  __syncthreads();
  int base = 0;
  #pragma unroll
  for (int w = 0; w < 4; w++) if (w < wv) base += wtot[w];
  if (i < Nn) row_start[i] = base + incl - v;
  if (t == 255) bsum[blockIdx.x] = base + incl;
}

// single-wave exclusive scan of NB2 (=40) block sums
__global__ __launch_bounds__(64) void k_scan2(int* __restrict__ bsum,
    int* __restrict__ row_start){
  int lane = threadIdx.x;
  int v = (lane < NB2) ? bsum[lane] : 0;
  int incl = v;
  #pragma unroll
  for (int d = 1; d < 64; d <<= 1){
    int y = __shfl_up(incl, d);
    if (lane >= d) incl += y;
  }
  if (lane < NB2) bsum[lane] = incl - v;
  if (lane == 0) row_start[Nn] = Me;
}

__global__ __launch_bounds__(256) void k_scan3(int* __restrict__ row_start,
    const int* __restrict__ bsum){
  int i = blockIdx.x*256 + threadIdx.x;
  if (i < Nn) row_start[i] += bsum[blockIdx.x];
}

__global__ void k_scatter(const int* __restrict__ eidx,
    const int* __restrict__ row_start, int* __restrict__ cursor,
    int* __restrict__ csr){
  int e = blockIdx.x*256 + threadIdx.x;
  if (e >= Me) return;
  int s = eidx[e], d = eidx[Me + e];
  int p = row_start[d] + atomicAdd(&cursor[d], 1);
  csr[p] = s;
}

// ---------------- GAT aggregation layer 0/1 (template CSR + inline self-loop) ----------------
__global__ __launch_bounds__(256) void k_gat128(const float* __restrict__ ht,
    const float* __restrict__ alS, const float* __restrict__ alD,
    const int* __restrict__ row_start, const int* __restrict__ csr,
    const float* __restrict__ gb, const float* __restrict__ lng,
    const float* __restrict__ lnb, __hip_bfloat16* __restrict__ outH, int n){
  __shared__ float4 wbuf[4][64];
  __shared__ int    sbuf[4][64];
  int wave = threadIdx.x >> 6, lane = threadIdx.x & 63;
  int dd = blockIdx.x*4 + wave;
  if (dd >= n) return;
  int tr  = (dd >= Nn) ? dd - Nn : dd;
  int off = (dd >= Nn) ? Nn : 0;
  int c0 = lane, c1 = lane + 64;
  bool h0  = (c0 >> 5) != 0;   // c0 in head 1?
  bool h13 = (c1 >> 5) == 3;   // c1 in head 3?
  float4 ald4 = *(const float4*)(alD + dd*4);
  int begin = row_start[tr], end = row_start[tr+1];

  // self-loop term
  float4 asl = *(const float4*)(alS + dd*4);
  float4 wsl;
  wsl.x = __expf(leaky(asl.x + ald4.x));
  wsl.y = __expf(leaky(asl.y + ald4.y));
  wsl.z = __expf(leaky(asl.z + ald4.z));
  wsl.w = __expf(leaky(asl.w + ald4.w));
  float e0s = h0  ? wsl.y : wsl.x;
  float e1s = h13 ? wsl.w : wsl.z;
  float den0 = e0s, den1 = e1s;
  float acc0 = e0s * ht[(size_t)dd*128 + c0];
  float acc1 = e1s * ht[(size_t)dd*128 + c1];

  const float* __restrict__ ht0p = ht + c0;
  const float* __restrict__ ht1p = ht + c1;

  for (int j = begin; j < end; j += 64){
    int nc = min(64, end - j);
    // phase A: one edge per lane -> weights into wave-private LDS
    if (lane < nc){
      int s = csr[j + lane] + off;
      float4 as4 = *(const float4*)(alS + s*4);
      float4 w;
      w.x = __expf(leaky(as4.x + ald4.x));
      w.y = __expf(leaky(as4.y + ald4.y));
      w.z = __expf(leaky(as4.z + ald4.z));
      w.w = __expf(leaky(as4.w + ald4.w));
      wbuf[wave][lane] = w;
      sbuf[wave][lane] = s;
    }
    // phase B: column-parallel FMA (LDS reads are uniform-address broadcasts)
    int q = 0;
    for (; q + 8 <= nc; q += 8){
      int sv[8]; float4 wv[8];
      #pragma unroll
      for (int u=0;u<8;u++){ sv[u] = sbuf[wave][q+u]; wv[u] = wbuf[wave][q+u]; }
      float hv0[8], hv1[8];
      #pragma unroll
      for (int u=0;u<8;u++){
        hv0[u] = ht0p[(size_t)sv[u]*128];
        hv1[u] = ht1p[(size_t)sv[u]*128];
      }
      #pragma unroll
      for (int u=0;u<8;u++){
        float e0 = h0  ? wv[u].y : wv[u].x;
        float e1 = h13 ? wv[u].w : wv[u].z;
        den0 += e0; den1 += e1;
        acc0 += e0*hv0[u]; acc1 += e1*hv1[u];
      }
    }
    for (; q < nc; q++){
      int s = sbuf[wave][q]; float4 w = wbuf[wave][q];
      float e0 = h0  ? w.y : w.x;
      float e1 = h13 ? w.w : w.z;
      den0 += e0; den1 += e1;
      acc0 += e0*ht0p[(size_t)s*128]; acc1 += e1*ht1p[(size_t)s*128];
    }
  }
  float v0 = acc0 / (den0 + 1e-16f) + gb[c0];
  float v1 = acc1 / (den1 + 1e-16f) + gb[c1];

  // LayerNorm over 128 features held by this wave (2 per lane)
  float sum = v0 + v1, sq = v0*v0 + v1*v1;
  #pragma unroll
  for (int offx = 32; offx; offx >>= 1){
    sum += __shfl_xor(sum, offx);
    sq  += __shfl_xor(sq,  offx);
  }
  float mu  = sum * (1.f/128.f);
  float var = sq  * (1.f/128.f) - mu*mu;
  float inv = rsqrtf(var + 1e-5f);
  float y0 = (v0 - mu)*inv*lng[c0] + lnb[c0];
  float y1 = (v1 - mu)*inv*lng[c1] + lnb[c1];
  outH[(size_t)dd*128 + c0] = __float2bfloat16(leaky(y0));
  outH[(size_t)dd*128 + c1] = __float2bfloat16(leaky(y1));
}

// ---------------- GAT output layer (1 head, 67 cols) + residual + write ----------------
__global__ __launch_bounds__(256) void k_gat_out(const float* __restrict__ ht2,
    const float* __restrict__ alS, const float* __restrict__ alD,
    const int* __restrict__ row_start, const int* __restrict__ csr,
    const float* __restrict__ gb2, const float* __restrict__ x,
    const float* __restrict__ pos, float* __restrict__ out, int n){
  __shared__ float wbuf[4][64];
  __shared__ int   sbuf[4][64];
  int wave = threadIdx.x >> 6, lane = threadIdx.x & 63;
  int dd = blockIdx.x*4 + wave;
  if (dd >= n) return;
  int tr  = (dd >= Nn) ? dd - Nn : dd;
  int off = (dd >= Nn) ? Nn : 0;
  int c0 = lane, c1 = lane + 64;
  bool has1 = (c1 < 67);
  float ald = alD[dd];
  int begin = row_start[tr], end = row_start[tr+1];

  // self-loop term
  float wsl = __expf(leaky(alS[dd] + ald));
  float den  = wsl;
  float acc0 = wsl * ht2[(size_t)dd*68 + c0];
  float acc1 = has1 ? wsl * ht2[(size_t)dd*68 + c1] : 0.f;

  const float* __restrict__ h0p = ht2 + c0;
  const float* __restrict__ h1p = ht2 + c1;

  for (int j = begin; j < end; j += 64){
    int nc = min(64, end - j);
    if (lane < nc){
      int s = csr[j + lane] + off;
      wbuf[wave][lane] = __expf(leaky(alS[s] + ald));
      sbuf[wave][lane] = s;
    }
    int q = 0;
    for (; q + 8 <= nc; q += 8){
      int sv[8]; float wv[8];
      #pragma unroll
      for (int u=0;u<8;u++){ sv[u] = sbuf[wave][q+u]; wv[u] = wbuf[wave][q+u]; }
      float hv0[8], hv1[8];
      #pragma unroll
      for (int u=0;u<8;u++){
        hv0[u] = h0p[(size_t)sv[u]*68];
        hv1[u] = has1 ? h1p[(size_t)sv[u]*68] : 0.f;
      }
      #pragma unroll
      for (int u=0;u<8;u++){
        den  += wv[u];
        acc0 += wv[u]*hv0[u];
        acc1 += wv[u]*hv1[u];
      }
    }
    for (; q < nc; q++){
      int s = sbuf[wave][q]; float w = wbuf[wave][q];
      den += w;
      acc0 += w*h0p[(size_t)s*68];
      if (has1) acc1 += w*h1p[(size_t)s*68];
    }
  }
  float idn = 1.f / (den + 1e-16f);
  int i = tr;
  float v0 = acc0*idn + gb2[c0];
  if (c0 < 3) out[NT*64 + dd*3 + c0] = pos[i*3 + c0] + v0;
  else        out[dd*64 + (c0-3)]    = x[i*64 + (c0-3)] + v0;
  if (has1){
    float v1 = acc1*idn + gb2[c1];
    out[dd*64 + (c1-3)] = x[i*64 + (c1-3)] + v1;
  }
}

extern "C" void kernel_launch(void* const* d_in, const int* in_sizes, int n_in,
                              void* d_out, int out_size, void* d_ws, size_t ws_size,
                              hipStream_t stream){
  const float* z    = (const float*)d_in[0];
  const float* x    = (const float*)d_in[1];
  const float* pos  = (const float*)d_in[2];
  const int*   eidx = (const int*)  d_in[3];
  const float* w1   = (const float*)d_in[4];
  const float* b1   = (const float*)d_in[5];
  const float* w2   = (const float*)d_in[6];
  const float* b2   = (const float*)d_in[7];
  const float* w3   = (const float*)d_in[8];
  const float* b3   = (const float*)d_in[9];
  const float* gw0  = (const float*)d_in[10];
  const float* ga0s = (const float*)d_in[11];
  const float* ga0d = (const float*)d_in[12];
  const float* gb0  = (const float*)d_in[13];
  const float* gw1  = (const float*)d_in[14];
  const float* ga1s = (const float*)d_in[15];
  const float* ga1d = (const float*)d_in[16];
  const float* gb1  = (const float*)d_in[17];
  const float* gw2  = (const float*)d_in[18];
  const float* ga2s = (const float*)d_in[19];
  const float* ga2d = (const float*)d_in[20];
  const float* gb2  = (const float*)d_in[21];
  const float* ln0g = (const float*)d_in[22];
  const float* ln0b = (const float*)d_in[23];
  const float* ln1g = (const float*)d_in[24];
  const float* ln1b = (const float*)d_in[25];
  float* out = (float*)d_out;

  float* ws       = (float*)d_ws;
  float* styleW0  = ws;                  // 256
  float* alS      = ws + 256;            // 80000
  float* alD      = alS + 80000;         // 80000
  float* bufA     = alD + 80000;         // NT*128 f32
  __hip_bfloat16* bufB = (__hip_bfloat16*)(bufA + NT*128);  // NT*128 bf16
  int*   cnt      = (int*)(bufA + 2*NT*128); // Nn
  int*   cursor   = cnt + Nn;                // Nn
  int*   bsum     = cursor + Nn;             // 64
  int*   row_start= bsum + 64;               // Nn+1
  int*   csr      = row_start + Nn + 1;      // Me

  // style path
  k_style<<<1, 512, 0, stream>>>(z, w1, b1, w2, b2, w3, b3, gw0, styleW0);

  // CSR by dst (template graph only)
  hipMemsetAsync(cnt, 0, 2*Nn*sizeof(int), stream);   // cnt + cursor
  k_hist<<<(Me+255)/256, 256, 0, stream>>>(eidx, cnt);
  k_scan1<<<NB2, 256, 0, stream>>>(cnt, row_start, bsum);
  k_scan2<<<1, 64, 0, stream>>>(bsum, row_start);
  k_scan3<<<NB2, 256, 0, stream>>>(row_start, bsum);
  k_scatter<<<(Me+255)/256, 256, 0, stream>>>(eidx, row_start, cursor, csr);

  const int MB = (NT+127)/128;
  // layer 0
  k_ht0<<<(Nn+31)/32, 256, 0, stream>>>(x, gw0, styleW0, bufA);
  k_al<<<(NT*4+255)/256, 256, 0, stream>>>(bufA, ga0s, ga0d, alS, alD, NT);
  k_gat128<<<(NT+3)/4, 256, 0, stream>>>(bufA, alS, alD, row_start, csr,
                                         gb0, ln0g, ln0b, bufB, NT);
  // layer 1
  k_mm_mfma<128,128,8><<<MB, 256, 0, stream>>>((const ushort*)bufB, gw1, bufA, NT);
  k_al<<<(NT*4+255)/256, 256, 0, stream>>>(bufA, ga1s, ga1d, alS, alD, NT);
  k_gat128<<<(NT+3)/4, 256, 0, stream>>>(bufA, alS, alD, row_start, csr,
                                         gb1, ln1g, ln1b, bufB, NT);
  // layer 2 (1 head, 67 outputs, fused residual + final write)
  k_mm_mfma<67,68,5><<<MB, 256, 0, stream>>>((const ushort*)bufB, gw2, bufA, NT);
  k_al2<<<(NT+255)/256, 256, 0, stream>>>(bufA, ga2s, ga2d, alS, alD, NT);
  k_gat_out<<<(NT+3)/4, 256, 0, stream>>>(bufA, alS, alD, row_start, csr,
                                          gb2, x, pos, out, NT);
}

// Round 6
// 210.372 us; speedup vs baseline: 1.8294x; 1.0859x over previous
//
#include <hip/hip_runtime.h>
#include <hip/hip_bf16.h>

#define DEV_INLINE __device__ __forceinline__

constexpr int Nn   = 10000;     // nodes per batch
constexpr int NT   = 20000;     // B*N
constexpr int Me   = 320000;    // template edges
constexpr int NB2  = (Nn + 255) / 256;  // scan blocks over template nodes = 40
constexpr float NEG = 0.2f;

typedef float  f32x4  __attribute__((ext_vector_type(4)));
typedef short  bf16x8 __attribute__((ext_vector_type(8)));

DEV_INLINE float leaky(float x){ return x >= 0.f ? x : NEG*x; }

DEV_INLINE ushort f2bf(float v){
  __hip_bfloat16 h = __float2bfloat16(v);
  return *reinterpret_cast<ushort*>(&h);
}

// ---------------- generic small MLP stage: out[2*OD] = act(in[2,K] @ W[K,OD] + b) ----------------
// one wave per output element; lanes split K then shuffle-reduce.
template<int K>
__global__ __launch_bounds__(256) void k_mlp(const float* __restrict__ in,
    const float* __restrict__ W, const float* __restrict__ bias,
    float* __restrict__ out, int OD, int doAct){
  int wave = threadIdx.x >> 6, lane = threadIdx.x & 63;
  int o = blockIdx.x*4 + wave;
  if (o >= 2*OD) return;
  int b = (o >= OD) ? 1 : 0;
  int j = o - b*OD;
  const float* __restrict__ ip = in + b*K;
  float acc = 0.f;
  #pragma unroll 2
  for (int k = lane; k < K; k += 64) acc += ip[k] * W[(size_t)k*OD + j];
  #pragma unroll
  for (int off = 32; off; off >>= 1) acc += __shfl_xor(acc, off);
  if (lane == 0){
    float v = acc + (bias ? bias[j] : 0.f);
    out[o] = doAct ? leaky(v) : v;
  }
}

// ---------------- zero int buffer ----------------
__global__ __launch_bounds__(256) void k_zero(int* __restrict__ p, int n){
  int i = blockIdx.x*256 + threadIdx.x;
  if (i < n) p[i] = 0;
}

// ---------------- ht0 = x @ gw0[:64,:] + styleW0[b]  (both batches) ----------------
__global__ __launch_bounds__(256) void k_ht0(const float* __restrict__ x,
    const float* __restrict__ gw0, const float* __restrict__ styleW0,
    float* __restrict__ ht0){
  __shared__ float wl[64][128];
  __shared__ float xl[32][64];
  __shared__ float sw[2][128];
  int t = threadIdx.x;
  for (int i=t; i<64*128; i+=256) wl[i>>7][i&127] = gw0[i];
  if (t < 256) sw[t>>7][t&127] = styleW0[t];
  int row0 = blockIdx.x*32;
  for (int i=t; i<32*64; i+=256){
    int r = i>>6, c = i&63; int gr = row0 + r;
    xl[r][c] = (gr < Nn) ? x[gr*64 + c] : 0.f;
  }
  __syncthreads();
  int c = t & 127, rh = t >> 7;
  float acc[16];
  #pragma unroll
  for (int i=0;i<16;i++) acc[i]=0.f;
  for (int k=0;k<64;k++){
    float w = wl[k][c];
    #pragma unroll
    for (int i=0;i<16;i++) acc[i] += xl[rh+2*i][k]*w;
  }
  float s0 = sw[0][c], s1 = sw[1][c];
  #pragma unroll
  for (int i=0;i<16;i++){
    int gr = row0 + rh + 2*i;
    if (gr < Nn){
      ht0[gr*128 + c]        = acc[i] + s0;
      ht0[(Nn+gr)*128 + c]   = acc[i] + s1;
    }
  }
}

// ---------------- MFMA matmul: out[M,LDO](f32) = A[M,128](bf16) @ W[128,NCOL](f32) ----------------
template<int NCOL, int LDO, int NF>
__global__ __launch_bounds__(256) void k_mm_mfma(const ushort* __restrict__ A,
    const float* __restrict__ W, float* __restrict__ out, int M){
  constexpr int NCOLP = NF*16;
  __shared__ ushort bt[NCOLP*128];  // Bt[c][k], XOR-swizzled
  int t = threadIdx.x;
  int wid = t >> 6, lane = t & 63, l15 = lane & 15, g = lane >> 4;
  int mbase = blockIdx.x*128 + wid*32;

  // issue A-fragment loads early (direct global->reg, bf16 already)
  bf16x8 afr[2][4];
  #pragma unroll
  for (int mf=0; mf<2; mf++){
    int row = mbase + mf*16 + l15;
    int rc = row < M ? row : M-1;
    const ushort* ap = A + (size_t)rc*128 + g*8;
    #pragma unroll
    for (int ks=0; ks<4; ks++)
      afr[mf][ks] = *(const bf16x8*)(ap + ks*32);
  }

  // stage W -> LDS transposed bf16 with XOR swizzle (byte ^= (c&7)<<4)
  for (int idx = t; idx < 128*NCOLP; idx += 256){
    int k = idx / NCOLP, c = idx % NCOLP;
    float v = (c < NCOL) ? W[k*NCOL + c] : 0.f;
    uint byte = ((uint)(c*128 + k) << 1) ^ ((uint)(c&7) << 4);
    *(ushort*)((char*)bt + byte) = f2bf(v);
  }
  __syncthreads();

  f32x4 acc[2][NF];
  #pragma unroll
  for (int mf=0; mf<2; mf++)
    #pragma unroll
    for (int nf=0; nf<NF; nf++) acc[mf][nf] = (f32x4){0.f,0.f,0.f,0.f};

  #pragma unroll
  for (int ks=0; ks<4; ks++){
    int kb = ks*32 + g*8;
    bf16x8 bfr[NF];
    #pragma unroll
    for (int nf=0; nf<NF; nf++){
      int c = nf*16 + l15;
      uint byte = ((uint)(c*128 + kb) << 1) ^ ((uint)(c&7) << 4);
      bfr[nf] = *(const bf16x8*)((const char*)bt + byte);
    }
    #pragma unroll
    for (int mf=0; mf<2; mf++)
      #pragma unroll
      for (int nf=0; nf<NF; nf++)
        acc[mf][nf] = __builtin_amdgcn_mfma_f32_16x16x32_bf16(
            afr[mf][ks], bfr[nf], acc[mf][nf], 0, 0, 0);
  }

  // C/D layout: col = lane&15, row = (lane>>4)*4 + r   [m89-verified]
  #pragma unroll
  for (int mf=0; mf<2; mf++){
    int rbase = mbase + mf*16 + g*4;
    #pragma unroll
    for (int nf=0; nf<NF; nf++){
      int c = nf*16 + l15;
      if (c < NCOL){
        #pragma unroll
        for (int r=0; r<4; r++){
          int row = rbase + r;
          if (row < M) out[(size_t)row*LDO + c] = acc[mf][nf][r];
        }
      }
    }
  }
}

// ---------------- per-node attention logits (4 heads x 32) ----------------
__global__ __launch_bounds__(256) void k_al(const float* __restrict__ ht,
    const float* __restrict__ a_s, const float* __restrict__ a_d,
    float* __restrict__ alS, float* __restrict__ alD, int n){
  int g = blockIdx.x*256 + threadIdx.x;
  if (g >= n*4) return;
  int node = g >> 2, h = g & 3;
  const float* row = ht + node*128 + h*32;
  float s = 0.f, dd = 0.f;
  #pragma unroll
  for (int k=0;k<32;k++){ float v = row[k]; s += v*a_s[h*32+k]; dd += v*a_d[h*32+k]; }
  alS[g] = s; alD[g] = dd;
}

// ---------------- per-node attention logits for layer 2 (1 head x 67) ----------------
__global__ __launch_bounds__(256) void k_al2(const float* __restrict__ ht2,
    const float* __restrict__ a_s, const float* __restrict__ a_d,
    float* __restrict__ alS, float* __restrict__ alD, int n){
  int g = blockIdx.x*256 + threadIdx.x;
  if (g >= n) return;
  const float* row = ht2 + g*68;
  float s = 0.f, dd = 0.f;
  #pragma unroll
  for (int k=0;k<67;k++){ float v = row[k]; s += v*a_s[k]; dd += v*a_d[k]; }
  alS[g] = s; alD[g] = dd;
}

// ---------------- CSR build (TEMPLATE graph only: Me edges, Nn nodes) ----------------
__global__ void k_hist(const int* __restrict__ eidx, int* __restrict__ cnt){
  int e = blockIdx.x*256 + threadIdx.x;
  if (e >= Me) return;
  atomicAdd(&cnt[eidx[Me + e]], 1);
}

// block-local exclusive scan of cnt -> row_start, block totals -> bsum
__global__ __launch_bounds__(256) void k_scan1(const int* __restrict__ cnt,
    int* __restrict__ row_start, int* __restrict__ bsum){
  __shared__ int wtot[4];
  int t = threadIdx.x, lane = t & 63, wv = t >> 6;
  int i = blockIdx.x*256 + t;
  int v = (i < Nn) ? cnt[i] : 0;
  int incl = v;
  #pragma unroll
  for (int d = 1; d < 64; d <<= 1){
    int y = __shfl_up(incl, d);
    if (lane >= d) incl += y;
  }
  if (lane == 63) wtot[wv] = incl;
  __syncthreads();
  int base = 0;
  #pragma unroll
  for (int w = 0; w < 4; w++) if (w < wv) base += wtot[w];
  if (i < Nn) row_start[i] = base + incl - v;
  if (t == 255) bsum[blockIdx.x] = base + incl;
}

// single-wave exclusive scan of NB2 (=40) block sums
__global__ __launch_bounds__(64) void k_scan2(int* __restrict__ bsum,
    int* __restrict__ row_start){
  int lane = threadIdx.x;
  int v = (lane < NB2) ? bsum[lane] : 0;
  int incl = v;
  #pragma unroll
  for (int d = 1; d < 64; d <<= 1){
    int y = __shfl_up(incl, d);
    if (lane >= d) incl += y;
  }
  if (lane < NB2) bsum[lane] = incl - v;
  if (lane == 0) row_start[Nn] = Me;
}

__global__ __launch_bounds__(256) void k_scan3(int* __restrict__ row_start,
    const int* __restrict__ bsum){
  int i = blockIdx.x*256 + threadIdx.x;
  if (i < Nn) row_start[i] += bsum[blockIdx.x];
}

__global__ void k_scatter(const int* __restrict__ eidx,
    const int* __restrict__ row_start, int* __restrict__ cursor,
    int* __restrict__ csr){
  int e = blockIdx.x*256 + threadIdx.x;
  if (e >= Me) return;
  int s = eidx[e], d = eidx[Me + e];
  int p = row_start[d] + atomicAdd(&cursor[d], 1);
  csr[p] = s;
}

// ---------------- GAT aggregation layer 0/1 (template CSR + inline self-loop) ----------------
__global__ __launch_bounds__(256) void k_gat128(const float* __restrict__ ht,
    const float* __restrict__ alS, const float* __restrict__ alD,
    const int* __restrict__ row_start, const int* __restrict__ csr,
    const float* __restrict__ gb, const float* __restrict__ lng,
    const float* __restrict__ lnb, __hip_bfloat16* __restrict__ outH, int n){
  __shared__ float4 wbuf[4][64];
  __shared__ int    sbuf[4][64];
  int wave = threadIdx.x >> 6, lane = threadIdx.x & 63;
  int dd = blockIdx.x*4 + wave;
  if (dd >= n) return;
  int tr  = (dd >= Nn) ? dd - Nn : dd;
  int off = (dd >= Nn) ? Nn : 0;
  int c0 = lane, c1 = lane + 64;
  bool h0  = (c0 >> 5) != 0;   // c0 in head 1?
  bool h13 = (c1 >> 5) == 3;   // c1 in head 3?
  float4 ald4 = *(const float4*)(alD + dd*4);
  int begin = row_start[tr], end = row_start[tr+1];

  // self-loop term
  float4 asl = *(const float4*)(alS + dd*4);
  float4 wsl;
  wsl.x = __expf(leaky(asl.x + ald4.x));
  wsl.y = __expf(leaky(asl.y + ald4.y));
  wsl.z = __expf(leaky(asl.z + ald4.z));
  wsl.w = __expf(leaky(asl.w + ald4.w));
  float e0s = h0  ? wsl.y : wsl.x;
  float e1s = h13 ? wsl.w : wsl.z;
  float den0 = e0s, den1 = e1s;
  float acc0 = e0s * ht[(size_t)dd*128 + c0];
  float acc1 = e1s * ht[(size_t)dd*128 + c1];

  const float* __restrict__ ht0p = ht + c0;
  const float* __restrict__ ht1p = ht + c1;

  for (int j = begin; j < end; j += 64){
    int nc = min(64, end - j);
    // phase A: one edge per lane -> weights into wave-private LDS
    if (lane < nc){
      int s = csr[j + lane] + off;
      float4 as4 = *(const float4*)(alS + s*4);
      float4 w;
      w.x = __expf(leaky(as4.x + ald4.x));
      w.y = __expf(leaky(as4.y + ald4.y));
      w.z = __expf(leaky(as4.z + ald4.z));
      w.w = __expf(leaky(as4.w + ald4.w));
      wbuf[wave][lane] = w;
      sbuf[wave][lane] = s;
    }
    // phase B: column-parallel FMA (LDS reads are uniform-address broadcasts)
    int q = 0;
    for (; q + 8 <= nc; q += 8){
      int sv[8]; float4 wv[8];
      #pragma unroll
      for (int u=0;u<8;u++){ sv[u] = sbuf[wave][q+u]; wv[u] = wbuf[wave][q+u]; }
      float hv0[8], hv1[8];
      #pragma unroll
      for (int u=0;u<8;u++){
        hv0[u] = ht0p[(size_t)sv[u]*128];
        hv1[u] = ht1p[(size_t)sv[u]*128];
      }
      #pragma unroll
      for (int u=0;u<8;u++){
        float e0 = h0  ? wv[u].y : wv[u].x;
        float e1 = h13 ? wv[u].w : wv[u].z;
        den0 += e0; den1 += e1;
        acc0 += e0*hv0[u]; acc1 += e1*hv1[u];
      }
    }
    for (; q < nc; q++){
      int s = sbuf[wave][q]; float4 w = wbuf[wave][q];
      float e0 = h0  ? w.y : w.x;
      float e1 = h13 ? w.w : w.z;
      den0 += e0; den1 += e1;
      acc0 += e0*ht0p[(size_t)s*128]; acc1 += e1*ht1p[(size_t)s*128];
    }
  }
  float v0 = acc0 / (den0 + 1e-16f) + gb[c0];
  float v1 = acc1 / (den1 + 1e-16f) + gb[c1];

  // LayerNorm over 128 features held by this wave (2 per lane)
  float sum = v0 + v1, sq = v0*v0 + v1*v1;
  #pragma unroll
  for (int offx = 32; offx; offx >>= 1){
    sum += __shfl_xor(sum, offx);
    sq  += __shfl_xor(sq,  offx);
  }
  float mu  = sum * (1.f/128.f);
  float var = sq  * (1.f/128.f) - mu*mu;
  float inv = rsqrtf(var + 1e-5f);
  float y0 = (v0 - mu)*inv*lng[c0] + lnb[c0];
  float y1 = (v1 - mu)*inv*lng[c1] + lnb[c1];
  outH[(size_t)dd*128 + c0] = __float2bfloat16(leaky(y0));
  outH[(size_t)dd*128 + c1] = __float2bfloat16(leaky(y1));
}

// ---------------- GAT output layer (1 head, 67 cols) + residual + write ----------------
__global__ __launch_bounds__(256) void k_gat_out(const float* __restrict__ ht2,
    const float* __restrict__ alS, const float* __restrict__ alD,
    const int* __restrict__ row_start, const int* __restrict__ csr,
    const float* __restrict__ gb2, const float* __restrict__ x,
    const float* __restrict__ pos, float* __restrict__ out, int n){
  __shared__ float wbuf[4][64];
  __shared__ int   sbuf[4][64];
  int wave = threadIdx.x >> 6, lane = threadIdx.x & 63;
  int dd = blockIdx.x*4 + wave;
  if (dd >= n) return;
  int tr  = (dd >= Nn) ? dd - Nn : dd;
  int off = (dd >= Nn) ? Nn : 0;
  int c0 = lane, c1 = lane + 64;
  bool has1 = (c1 < 67);
  float ald = alD[dd];
  int begin = row_start[tr], end = row_start[tr+1];

  // self-loop term
  float wsl = __expf(leaky(alS[dd] + ald));
  float den  = wsl;
  float acc0 = wsl * ht2[(size_t)dd*68 + c0];
  float acc1 = has1 ? wsl * ht2[(size_t)dd*68 + c1] : 0.f;

  const float* __restrict__ h0p = ht2 + c0;
  const float* __restrict__ h1p = ht2 + c1;

  for (int j = begin; j < end; j += 64){
    int nc = min(64, end - j);
    if (lane < nc){
      int s = csr[j + lane] + off;
      wbuf[wave][lane] = __expf(leaky(alS[s] + ald));
      sbuf[wave][lane] = s;
    }
    int q = 0;
    for (; q + 8 <= nc; q += 8){
      int sv[8]; float wv[8];
      #pragma unroll
      for (int u=0;u<8;u++){ sv[u] = sbuf[wave][q+u]; wv[u] = wbuf[wave][q+u]; }
      float hv0[8], hv1[8];
      #pragma unroll
      for (int u=0;u<8;u++){
        hv0[u] = h0p[(size_t)sv[u]*68];
        hv1[u] = has1 ? h1p[(size_t)sv[u]*68] : 0.f;
      }
      #pragma unroll
      for (int u=0;u<8;u++){
        den  += wv[u];
        acc0 += wv[u]*hv0[u];
        acc1 += wv[u]*hv1[u];
      }
    }
    for (; q < nc; q++){
      int s = sbuf[wave][q]; float w = wbuf[wave][q];
      den += w;
      acc0 += w*h0p[(size_t)s*68];
      if (has1) acc1 += w*h1p[(size_t)s*68];
    }
  }
  float idn = 1.f / (den + 1e-16f);
  int i = tr;
  float v0 = acc0*idn + gb2[c0];
  if (c0 < 3) out[NT*64 + dd*3 + c0] = pos[i*3 + c0] + v0;
  else        out[dd*64 + (c0-3)]    = x[i*64 + (c0-3)] + v0;
  if (has1){
    float v1 = acc1*idn + gb2[c1];
    out[dd*64 + (c1-3)] = x[i*64 + (c1-3)] + v1;
  }
}

extern "C" void kernel_launch(void* const* d_in, const int* in_sizes, int n_in,
                              void* d_out, int out_size, void* d_ws, size_t ws_size,
                              hipStream_t stream){
  const float* z    = (const float*)d_in[0];
  const float* x    = (const float*)d_in[1];
  const float* pos  = (const float*)d_in[2];
  const int*   eidx = (const int*)  d_in[3];
  const float* w1   = (const float*)d_in[4];
  const float* b1   = (const float*)d_in[5];
  const float* w2   = (const float*)d_in[6];
  const float* b2   = (const float*)d_in[7];
  const float* w3   = (const float*)d_in[8];
  const float* b3   = (const float*)d_in[9];
  const float* gw0  = (const float*)d_in[10];
  const float* ga0s = (const float*)d_in[11];
  const float* ga0d = (const float*)d_in[12];
  const float* gb0  = (const float*)d_in[13];
  const float* gw1  = (const float*)d_in[14];
  const float* ga1s = (const float*)d_in[15];
  const float* ga1d = (const float*)d_in[16];
  const float* gb1  = (const float*)d_in[17];
  const float* gw2  = (const float*)d_in[18];
  const float* ga2s = (const float*)d_in[19];
  const float* ga2d = (const float*)d_in[20];
  const float* gb2  = (const float*)d_in[21];
  const float* ln0g = (const float*)d_in[22];
  const float* ln0b = (const float*)d_in[23];
  const float* ln1g = (const float*)d_in[24];
  const float* ln1b = (const float*)d_in[25];
  float* out = (float*)d_out;

  float* ws       = (float*)d_ws;
  float* styleW0  = ws;                  // 256
  float* s1buf    = ws + 256;            // 512
  float* s2buf    = s1buf + 512;         // 1024
  float* stbuf    = s2buf + 1024;        // 256
  float* alS      = stbuf + 256;         // 80000
  float* alD      = alS + 80000;         // 80000
  float* bufA     = alD + 80000;         // NT*128 f32
  __hip_bfloat16* bufB = (__hip_bfloat16*)(bufA + NT*128);  // NT*128 bf16
  int*   cnt      = (int*)(bufA + 2*NT*128); // Nn
  int*   cursor   = cnt + Nn;                // Nn
  int*   bsum     = cursor + Nn;             // 64
  int*   row_start= bsum + 64;               // Nn+1
  int*   csr      = row_start + Nn + 1;      // Me

  // style path: z[2,128] -> s1[2,256] -> s2[2,512] -> style[2,128] -> styleW0[2,128]
  k_mlp<128><<<(2*256+3)/4, 256, 0, stream>>>(z,     w1, b1, s1buf, 256, 1);
  k_mlp<256><<<(2*512+3)/4, 256, 0, stream>>>(s1buf, w2, b2, s2buf, 512, 1);
  k_mlp<512><<<(2*128+3)/4, 256, 0, stream>>>(s2buf, w3, b3, stbuf, 128, 0);
  k_mlp<128><<<(2*128+3)/4, 256, 0, stream>>>(stbuf, gw0 + 64*128, (const float*)nullptr, styleW0, 128, 0);

  // CSR by dst (template graph only)
  k_zero<<<(2*Nn+255)/256, 256, 0, stream>>>(cnt, 2*Nn);   // cnt + cursor (contiguous)
  k_hist<<<(Me+255)/256, 256, 0, stream>>>(eidx, cnt);
  k_scan1<<<NB2, 256, 0, stream>>>(cnt, row_start, bsum);
  k_scan2<<<1, 64, 0, stream>>>(bsum, row_start);
  k_scan3<<<NB2, 256, 0, stream>>>(row_start, bsum);
  k_scatter<<<(Me+255)/256, 256, 0, stream>>>(eidx, row_start, cursor, csr);

  const int MB = (NT+127)/128;
  // layer 0
  k_ht0<<<(Nn+31)/32, 256, 0, stream>>>(x, gw0, styleW0, bufA);
  k_al<<<(NT*4+255)/256, 256, 0, stream>>>(bufA, ga0s, ga0d, alS, alD, NT);
  k_gat128<<<(NT+3)/4, 256, 0, stream>>>(bufA, alS, alD, row_start, csr,
                                         gb0, ln0g, ln0b, bufB, NT);
  // layer 1
  k_mm_mfma<128,128,8><<<MB, 256, 0, stream>>>((const ushort*)bufB, gw1, bufA, NT);
  k_al<<<(NT*4+255)/256, 256, 0, stream>>>(bufA, ga1s, ga1d, alS, alD, NT);
  k_gat128<<<(NT+3)/4, 256, 0, stream>>>(bufA, alS, alD, row_start, csr,
                                         gb1, ln1g, ln1b, bufB, NT);
  // layer 2 (1 head, 67 outputs, fused residual + final write)
  k_mm_mfma<67,68,5><<<MB, 256, 0, stream>>>((const ushort*)bufB, gw2, bufA, NT);
  k_al2<<<(NT+255)/256, 256, 0, stream>>>(bufA, ga2s, ga2d, alS, alD, NT);
  k_gat_out<<<(NT+3)/4, 256, 0, stream>>>(bufA, alS, alD, row_start, csr,
                                          gb2, x, pos, out, NT);
}

// Round 7
// 189.185 us; speedup vs baseline: 2.0342x; 1.1120x over previous
//
#include <hip/hip_runtime.h>
#include <hip/hip_bf16.h>

#define DEV_INLINE __device__ __forceinline__

constexpr int Nn   = 10000;     // nodes per batch
constexpr int NT   = 20000;     // B*N
constexpr int Me   = 320000;    // template edges
constexpr int NB2  = (Nn + 255) / 256;  // scan blocks over template nodes = 40
constexpr float NEG = 0.2f;

typedef float  f32x4  __attribute__((ext_vector_type(4)));
typedef short  bf16x8 __attribute__((ext_vector_type(8)));

DEV_INLINE float leaky(float x){ return x >= 0.f ? x : NEG*x; }

DEV_INLINE ushort f2bf(float v){
  __hip_bfloat16 h = __float2bfloat16(v);
  return *reinterpret_cast<ushort*>(&h);
}
DEV_INLINE float bf2f(ushort u){
  uint x = ((uint)u) << 16;
  return __uint_as_float(x);
}
DEV_INLINE float sel4(float4 w, int h){
  return h < 2 ? (h == 0 ? w.x : w.y) : (h == 2 ? w.z : w.w);
}

// ---------------- generic small MLP stage: out[2*OD] = act(in[2,K] @ W[K,OD] + b) ----------------
template<int K>
__global__ __launch_bounds__(256) void k_mlp(const float* __restrict__ in,
    const float* __restrict__ W, const float* __restrict__ bias,
    float* __restrict__ out, int OD, int doAct){
  int wave = threadIdx.x >> 6, lane = threadIdx.x & 63;
  int o = blockIdx.x*4 + wave;
  if (o >= 2*OD) return;
  int b = (o >= OD) ? 1 : 0;
  int j = o - b*OD;
  const float* __restrict__ ip = in + b*K;
  float acc = 0.f;
  #pragma unroll 2
  for (int k = lane; k < K; k += 64) acc += ip[k] * W[(size_t)k*OD + j];
  #pragma unroll
  for (int off = 32; off; off >>= 1) acc += __shfl_xor(acc, off);
  if (lane == 0){
    float v = acc + (bias ? bias[j] : 0.f);
    out[o] = doAct ? leaky(v) : v;
  }
}

// ---------------- zero int buffer ----------------
__global__ __launch_bounds__(256) void k_zero(int* __restrict__ p, int n){
  int i = blockIdx.x*256 + threadIdx.x;
  if (i < n) p[i] = 0;
}

// ---------------- ht0(bf16) = x @ gw0[:64,:] + styleW0[b] ----------------
__global__ __launch_bounds__(256) void k_ht0(const float* __restrict__ x,
    const float* __restrict__ gw0, const float* __restrict__ styleW0,
    ushort* __restrict__ ht0){
  __shared__ float wl[64][128];
  __shared__ float xl[32][64];
  __shared__ float sw[2][128];
  int t = threadIdx.x;
  for (int i=t; i<64*128; i+=256) wl[i>>7][i&127] = gw0[i];
  if (t < 256) sw[t>>7][t&127] = styleW0[t];
  int row0 = blockIdx.x*32;
  for (int i=t; i<32*64; i+=256){
    int r = i>>6, c = i&63; int gr = row0 + r;
    xl[r][c] = (gr < Nn) ? x[gr*64 + c] : 0.f;
  }
  __syncthreads();
  int c = t & 127, rh = t >> 7;
  float acc[16];
  #pragma unroll
  for (int i=0;i<16;i++) acc[i]=0.f;
  for (int k=0;k<64;k++){
    float w = wl[k][c];
    #pragma unroll
    for (int i=0;i<16;i++) acc[i] += xl[rh+2*i][k]*w;
  }
  float s0 = sw[0][c], s1 = sw[1][c];
  #pragma unroll
  for (int i=0;i<16;i++){
    int gr = row0 + rh + 2*i;
    if (gr < Nn){
      ht0[(size_t)gr*128 + c]      = f2bf(acc[i] + s0);
      ht0[(size_t)(Nn+gr)*128 + c] = f2bf(acc[i] + s1);
    }
  }
}

// ---------------- MFMA matmul: out[M,LDO](bf16) = A[M,128](bf16) @ W[128,NCOL](f32) ----------------
template<int NCOL, int LDO, int NF>
__global__ __launch_bounds__(256) void k_mm_mfma(const ushort* __restrict__ A,
    const float* __restrict__ W, ushort* __restrict__ out, int M){
  constexpr int NCOLP = NF*16;
  __shared__ ushort bt[NCOLP*128];  // Bt[c][k], XOR-swizzled
  int t = threadIdx.x;
  int wid = t >> 6, lane = t & 63, l15 = lane & 15, g = lane >> 4;
  int mbase = blockIdx.x*128 + wid*32;

  bf16x8 afr[2][4];
  #pragma unroll
  for (int mf=0; mf<2; mf++){
    int row = mbase + mf*16 + l15;
    int rc = row < M ? row : M-1;
    const ushort* ap = A + (size_t)rc*128 + g*8;
    #pragma unroll
    for (int ks=0; ks<4; ks++)
      afr[mf][ks] = *(const bf16x8*)(ap + ks*32);
  }

  for (int idx = t; idx < 128*NCOLP; idx += 256){
    int k = idx / NCOLP, c = idx % NCOLP;
    float v = (c < NCOL) ? W[k*NCOL + c] : 0.f;
    uint byte = ((uint)(c*128 + k) << 1) ^ ((uint)(c&7) << 4);
    *(ushort*)((char*)bt + byte) = f2bf(v);
  }
  __syncthreads();

  f32x4 acc[2][NF];
  #pragma unroll
  for (int mf=0; mf<2; mf++)
    #pragma unroll
    for (int nf=0; nf<NF; nf++) acc[mf][nf] = (f32x4){0.f,0.f,0.f,0.f};

  #pragma unroll
  for (int ks=0; ks<4; ks++){
    int kb = ks*32 + g*8;
    bf16x8 bfr[NF];
    #pragma unroll
    for (int nf=0; nf<NF; nf++){
      int c = nf*16 + l15;
      uint byte = ((uint)(c*128 + kb) << 1) ^ ((uint)(c&7) << 4);
      bfr[nf] = *(const bf16x8*)((const char*)bt + byte);
    }
    #pragma unroll
    for (int mf=0; mf<2; mf++)
      #pragma unroll
      for (int nf=0; nf<NF; nf++)
        acc[mf][nf] = __builtin_amdgcn_mfma_f32_16x16x32_bf16(
            afr[mf][ks], bfr[nf], acc[mf][nf], 0, 0, 0);
  }

  // C/D layout: col = lane&15, row = (lane>>4)*4 + r
  #pragma unroll
  for (int mf=0; mf<2; mf++){
    int rbase = mbase + mf*16 + g*4;
    #pragma unroll
    for (int nf=0; nf<NF; nf++){
      int c = nf*16 + l15;
      if (c < LDO){
        #pragma unroll
        for (int r=0; r<4; r++){
          int row = rbase + r;
          if (row < M) out[(size_t)row*LDO + c] = (c < NCOL) ? f2bf(acc[mf][nf][r]) : (ushort)0;
        }
      }
    }
  }
}

// ---------------- per-node attention logits (4 heads x 32), bf16 input ----------------
__global__ __launch_bounds__(256) void k_al(const ushort* __restrict__ ht,
    const float* __restrict__ a_s, const float* __restrict__ a_d,
    float* __restrict__ alS, float* __restrict__ alD, int n){
  int g = blockIdx.x*256 + threadIdx.x;
  if (g >= n*4) return;
  int node = g >> 2, h = g & 3;
  const ushort* row = ht + (size_t)node*128 + h*32;
  float s = 0.f, dd = 0.f;
  #pragma unroll
  for (int k=0;k<32;k++){ float v = bf2f(row[k]); s += v*a_s[h*32+k]; dd += v*a_d[h*32+k]; }
  alS[g] = s; alD[g] = dd;
}

// ---------------- per-node attention logits for layer 2 (1 head x 67), bf16 input ----------------
__global__ __launch_bounds__(256) void k_al2(const ushort* __restrict__ ht2,
    const float* __restrict__ a_s, const float* __restrict__ a_d,
    float* __restrict__ alS, float* __restrict__ alD, int n){
  int g = blockIdx.x*256 + threadIdx.x;
  if (g >= n) return;
  const ushort* row = ht2 + (size_t)g*68;
  float s = 0.f, dd = 0.f;
  #pragma unroll
  for (int k=0;k<67;k++){ float v = bf2f(row[k]); s += v*a_s[k]; dd += v*a_d[k]; }
  alS[g] = s; alD[g] = dd;
}

// ---------------- CSR build (TEMPLATE graph only) ----------------
__global__ void k_hist(const int* __restrict__ eidx, int* __restrict__ cnt){
  int e = blockIdx.x*256 + threadIdx.x;
  if (e >= Me) return;
  atomicAdd(&cnt[eidx[Me + e]], 1);
}

__global__ __launch_bounds__(256) void k_scan1(const int* __restrict__ cnt,
    int* __restrict__ row_start, int* __restrict__ bsum){
  __shared__ int wtot[4];
  int t = threadIdx.x, lane = t & 63, wv = t >> 6;
  int i = blockIdx.x*256 + t;
  int v = (i < Nn) ? cnt[i] : 0;
  int incl = v;
  #pragma unroll
  for (int d = 1; d < 64; d <<= 1){
    int y = __shfl_up(incl, d);
    if (lane >= d) incl += y;
  }
  if (lane == 63) wtot[wv] = incl;
  __syncthreads();
  int base = 0;
  #pragma unroll
  for (int w = 0; w < 4; w++) if (w < wv) base += wtot[w];
  if (i < Nn) row_start[i] = base + incl - v;
  if (t == 255) bsum[blockIdx.x] = base + incl;
}

__global__ __launch_bounds__(64) void k_scan2(int* __restrict__ bsum,
    int* __restrict__ row_start){
  int lane = threadIdx.x;
  int v = (lane < NB2) ? bsum[lane] : 0;
  int incl = v;
  #pragma unroll
  for (int d = 1; d < 64; d <<= 1){
    int y = __shfl_up(incl, d);
    if (lane >= d) incl += y;
  }
  if (lane < NB2) bsum[lane] = incl - v;
  if (lane == 0) row_start[Nn] = Me;
}

__global__ __launch_bounds__(256) void k_scan3(int* __restrict__ row_start,
    const int* __restrict__ bsum){
  int i = blockIdx.x*256 + threadIdx.x;
  if (i < Nn) row_start[i] += bsum[blockIdx.x];
}

__global__ void k_scatter(const int* __restrict__ eidx,
    const int* __restrict__ row_start, int* __restrict__ cursor,
    int* __restrict__ csr){
  int e = blockIdx.x*256 + threadIdx.x;
  if (e >= Me) return;
  int s = eidx[e], d = eidx[Me + e];
  int p = row_start[d] + atomicAdd(&cursor[d], 1);
  csr[p] = s;
}

// ---------------- GAT aggregation layer 0/1, bf16 gathers, paired cols ----------------
// lane owns cols (2l, 2l+1); head h = lane>>4 shared by both cols.
__global__ __launch_bounds__(256) void k_gat128(const ushort* __restrict__ ht,
    const float* __restrict__ alS, const float* __restrict__ alD,
    const int* __restrict__ row_start, const int* __restrict__ csr,
    const float* __restrict__ gb, const float* __restrict__ lng,
    const float* __restrict__ lnb, ushort* __restrict__ outH, int n){
  __shared__ float4 wbuf[4][64];
  __shared__ int    sbuf[4][64];
  int wave = threadIdx.x >> 6, lane = threadIdx.x & 63;
  int dd = blockIdx.x*4 + wave;
  if (dd >= n) return;
  int tr  = (dd >= Nn) ? dd - Nn : dd;
  int off = (dd >= Nn) ? Nn : 0;
  int c0 = lane*2;
  int h  = lane >> 4;
  float4 ald4 = *(const float4*)(alD + dd*4);
  int begin = row_start[tr], end = row_start[tr+1];

  // self-loop term
  float4 asl = *(const float4*)(alS + dd*4);
  float4 wsl;
  wsl.x = __expf(leaky(asl.x + ald4.x));
  wsl.y = __expf(leaky(asl.y + ald4.y));
  wsl.z = __expf(leaky(asl.z + ald4.z));
  wsl.w = __expf(leaky(asl.w + ald4.w));
  float es = sel4(wsl, h);
  uint sv0 = *(const uint*)(ht + (size_t)dd*128 + c0);
  float den  = es;
  float acc0 = es * bf2f((ushort)(sv0 & 0xffff));
  float acc1 = es * bf2f((ushort)(sv0 >> 16));

  const ushort* __restrict__ htp = ht + c0;

  for (int j = begin; j < end; j += 64){
    int nc = min(64, end - j);
    // phase A: one edge per lane -> 4-head weights into wave-private LDS
    if (lane < nc){
      int s = csr[j + lane] + off;
      float4 as4 = *(const float4*)(alS + s*4);
      float4 w;
      w.x = __expf(leaky(as4.x + ald4.x));
      w.y = __expf(leaky(as4.y + ald4.y));
      w.z = __expf(leaky(as4.z + ald4.z));
      w.w = __expf(leaky(as4.w + ald4.w));
      wbuf[wave][lane] = w;
      sbuf[wave][lane] = s;
    }
    // phase B: column-parallel FMA (LDS reads broadcast)
    int q = 0;
    for (; q + 8 <= nc; q += 8){
      int sv[8]; float4 wv[8];
      #pragma unroll
      for (int u=0;u<8;u++){ sv[u] = sbuf[wave][q+u]; wv[u] = wbuf[wave][q+u]; }
      uint hv[8];
      #pragma unroll
      for (int u=0;u<8;u++) hv[u] = *(const uint*)(htp + (size_t)sv[u]*128);
      #pragma unroll
      for (int u=0;u<8;u++){
        float e = sel4(wv[u], h);
        den  += e;
        acc0 += e * bf2f((ushort)(hv[u] & 0xffff));
        acc1 += e * bf2f((ushort)(hv[u] >> 16));
      }
    }
    for (; q < nc; q++){
      int s = sbuf[wave][q];
      float e = sel4(wbuf[wave][q], h);
      uint hv = *(const uint*)(htp + (size_t)s*128);
      den  += e;
      acc0 += e * bf2f((ushort)(hv & 0xffff));
      acc1 += e * bf2f((ushort)(hv >> 16));
    }
  }
  float idn = 1.f / (den + 1e-16f);
  float v0 = acc0*idn + gb[c0];
  float v1 = acc1*idn + gb[c0+1];

  // LayerNorm over 128 features held by this wave (2 per lane)
  float sum = v0 + v1, sq = v0*v0 + v1*v1;
  #pragma unroll
  for (int offx = 32; offx; offx >>= 1){
    sum += __shfl_xor(sum, offx);
    sq  += __shfl_xor(sq,  offx);
  }
  float mu  = sum * (1.f/128.f);
  float var = sq  * (1.f/128.f) - mu*mu;
  float inv = rsqrtf(var + 1e-5f);
  float y0 = (v0 - mu)*inv*lng[c0]   + lnb[c0];
  float y1 = (v1 - mu)*inv*lng[c0+1] + lnb[c0+1];
  uint ow = (uint)f2bf(leaky(y0)) | ((uint)f2bf(leaky(y1)) << 16);
  *(uint*)(outH + (size_t)dd*128 + c0) = ow;
}

// ---------------- GAT output layer (1 head, 67 cols), bf16 gathers + residual ----------------
__global__ __launch_bounds__(256) void k_gat_out(const ushort* __restrict__ ht2,
    const float* __restrict__ alS, const float* __restrict__ alD,
    const int* __restrict__ row_start, const int* __restrict__ csr,
    const float* __restrict__ gb2, const float* __restrict__ x,
    const float* __restrict__ pos, float* __restrict__ out, int n){
  __shared__ float wbuf[4][64];
  __shared__ int   sbuf[4][64];
  int wave = threadIdx.x >> 6, lane = threadIdx.x & 63;
  int dd = blockIdx.x*4 + wave;
  if (dd >= n) return;
  int tr  = (dd >= Nn) ? dd - Nn : dd;
  int off = (dd >= Nn) ? Nn : 0;
  int c0 = lane*2;
  bool act = (c0 < 67);             // lane < 34
  float ald = alD[dd];
  int begin = row_start[tr], end = row_start[tr+1];

  // self-loop term
  float wsl = __expf(leaky(alS[dd] + ald));
  float den  = wsl;
  uint sv0 = act ? *(const uint*)(ht2 + (size_t)dd*68 + c0) : 0u;
  float acc0 = wsl * bf2f((ushort)(sv0 & 0xffff));
  float acc1 = wsl * bf2f((ushort)(sv0 >> 16));

  const ushort* __restrict__ h2p = ht2 + c0;

  for (int j = begin; j < end; j += 64){
    int nc = min(64, end - j);
    if (lane < nc){
      int s = csr[j + lane] + off;
      wbuf[wave][lane] = __expf(leaky(alS[s] + ald));
      sbuf[wave][lane] = s;
    }
    int q = 0;
    for (; q + 8 <= nc; q += 8){
      int sv[8]; float wv[8];
      #pragma unroll
      for (int u=0;u<8;u++){ sv[u] = sbuf[wave][q+u]; wv[u] = wbuf[wave][q+u]; }
      uint hv[8];
      #pragma unroll
      for (int u=0;u<8;u++) hv[u] = act ? *(const uint*)(h2p + (size_t)sv[u]*68) : 0u;
      #pragma unroll
      for (int u=0;u<8;u++){
        den  += wv[u];
        acc0 += wv[u] * bf2f((ushort)(hv[u] & 0xffff));
        acc1 += wv[u] * bf2f((ushort)(hv[u] >> 16));
      }
    }
    for (; q < nc; q++){
      int s = sbuf[wave][q]; float w = wbuf[wave][q];
      uint hv = act ? *(const uint*)(h2p + (size_t)s*68) : 0u;
      den  += w;
      acc0 += w * bf2f((ushort)(hv & 0xffff));
      acc1 += w * bf2f((ushort)(hv >> 16));
    }
  }
  if (!act) return;
  float idn = 1.f / (den + 1e-16f);
  int i = tr;
  int c1 = c0 + 1;
  float v0 = acc0*idn + gb2[c0];
  if (c0 < 3) out[NT*64 + dd*3 + c0] = pos[i*3 + c0] + v0;
  else        out[dd*64 + (c0-3)]    = x[i*64 + (c0-3)] + v0;
  if (c1 < 67){
    float v1 = acc1*idn + gb2[c1];
    if (c1 < 3) out[NT*64 + dd*3 + c1] = pos[i*3 + c1] + v1;
    else        out[dd*64 + (c1-3)]    = x[i*64 + (c1-3)] + v1;
  }
}

extern "C" void kernel_launch(void* const* d_in, const int* in_sizes, int n_in,
                              void* d_out, int out_size, void* d_ws, size_t ws_size,
                              hipStream_t stream){
  const float* z    = (const float*)d_in[0];
  const float* x    = (const float*)d_in[1];
  const float* pos  = (const float*)d_in[2];
  const int*   eidx = (const int*)  d_in[3];
  const float* w1   = (const float*)d_in[4];
  const float* b1   = (const float*)d_in[5];
  const float* w2   = (const float*)d_in[6];
  const float* b2   = (const float*)d_in[7];
  const float* w3   = (const float*)d_in[8];
  const float* b3   = (const float*)d_in[9];
  const float* gw0  = (const float*)d_in[10];
  const float* ga0s = (const float*)d_in[11];
  const float* ga0d = (const float*)d_in[12];
  const float* gb0  = (const float*)d_in[13];
  const float* gw1  = (const float*)d_in[14];
  const float* ga1s = (const float*)d_in[15];
  const float* ga1d = (const float*)d_in[16];
  const float* gb1  = (const float*)d_in[17];
  const float* gw2  = (const float*)d_in[18];
  const float* ga2s = (const float*)d_in[19];
  const float* ga2d = (const float*)d_in[20];
  const float* gb2  = (const float*)d_in[21];
  const float* ln0g = (const float*)d_in[22];
  const float* ln0b = (const float*)d_in[23];
  const float* ln1g = (const float*)d_in[24];
  const float* ln1b = (const float*)d_in[25];
  float* out = (float*)d_out;

  float* ws       = (float*)d_ws;
  float* styleW0  = ws;                  // 256
  float* s1buf    = ws + 256;            // 512
  float* s2buf    = s1buf + 512;         // 1024
  float* stbuf    = s2buf + 1024;        // 256
  float* alS      = stbuf + 256;         // 80000
  float* alD      = alS + 80000;         // 80000
  ushort* htA     = (ushort*)(alD + 80000);  // NT*128 bf16
  ushort* htB     = htA + (size_t)NT*128;    // NT*128 bf16
  ushort* ht2c    = htB + (size_t)NT*128;    // NT*68 bf16
  int*   cnt      = (int*)(ht2c + (size_t)NT*68); // Nn
  int*   cursor   = cnt + Nn;                // Nn
  int*   bsum     = cursor + Nn;             // 64
  int*   row_start= bsum + 64;               // Nn+1
  int*   csr      = row_start + Nn + 1;      // Me

  // style path: z[2,128] -> s1[2,256] -> s2[2,512] -> style[2,128] -> styleW0[2,128]
  k_mlp<128><<<(2*256+3)/4, 256, 0, stream>>>(z,     w1, b1, s1buf, 256, 1);
  k_mlp<256><<<(2*512+3)/4, 256, 0, stream>>>(s1buf, w2, b2, s2buf, 512, 1);
  k_mlp<512><<<(2*128+3)/4, 256, 0, stream>>>(s2buf, w3, b3, stbuf, 128, 0);
  k_mlp<128><<<(2*128+3)/4, 256, 0, stream>>>(stbuf, gw0 + 64*128, (const float*)nullptr, styleW0, 128, 0);

  // CSR by dst (template graph only)
  k_zero<<<(2*Nn+255)/256, 256, 0, stream>>>(cnt, 2*Nn);   // cnt + cursor (contiguous)
  k_hist<<<(Me+255)/256, 256, 0, stream>>>(eidx, cnt);
  k_scan1<<<NB2, 256, 0, stream>>>(cnt, row_start, bsum);
  k_scan2<<<1, 64, 0, stream>>>(bsum, row_start);
  k_scan3<<<NB2, 256, 0, stream>>>(row_start, bsum);
  k_scatter<<<(Me+255)/256, 256, 0, stream>>>(eidx, row_start, cursor, csr);

  const int MB = (NT+127)/128;
  // layer 0
  k_ht0<<<(Nn+31)/32, 256, 0, stream>>>(x, gw0, styleW0, htA);
  k_al<<<(NT*4+255)/256, 256, 0, stream>>>(htA, ga0s, ga0d, alS, alD, NT);
  k_gat128<<<(NT+3)/4, 256, 0, stream>>>(htA, alS, alD, row_start, csr,
                                         gb0, ln0g, ln0b, htB, NT);
  // layer 1
  k_mm_mfma<128,128,8><<<MB, 256, 0, stream>>>(htB, gw1, htA, NT);
  k_al<<<(NT*4+255)/256, 256, 0, stream>>>(htA, ga1s, ga1d, alS, alD, NT);
  k_gat128<<<(NT+3)/4, 256, 0, stream>>>(htA, alS, alD, row_start, csr,
                                         gb1, ln1g, ln1b, htB, NT);
  // layer 2 (1 head, 67 outputs, fused residual + final write)
  k_mm_mfma<67,68,5><<<MB, 256, 0, stream>>>(htB, gw2, ht2c, NT);
  k_al2<<<(NT+255)/256, 256, 0, stream>>>(ht2c, ga2s, ga2d, alS, alD, NT);
  k_gat_out<<<(NT+3)/4, 256, 0, stream>>>(ht2c, alS, alD, row_start, csr,
                                          gb2, x, pos, out, NT);
}

// Round 8
// 185.530 us; speedup vs baseline: 2.0743x; 1.0197x over previous
//
#include <hip/hip_runtime.h>
#include <hip/hip_bf16.h>

#define DEV_INLINE __device__ __forceinline__

constexpr int Nn   = 10000;     // nodes per batch
constexpr int NT   = 20000;     // B*N
constexpr int Me   = 320000;    // template edges
constexpr float NEG = 0.2f;

typedef float  f32x4  __attribute__((ext_vector_type(4)));
typedef short  bf16x8 __attribute__((ext_vector_type(8)));

DEV_INLINE float leaky(float x){ return x >= 0.f ? x : NEG*x; }

DEV_INLINE ushort f2bf(float v){
  __hip_bfloat16 h = __float2bfloat16(v);
  return *reinterpret_cast<ushort*>(&h);
}
DEV_INLINE float bf2f(ushort u){
  uint x = ((uint)u) << 16;
  return __uint_as_float(x);
}
DEV_INLINE float sel4(float4 w, int h){
  return h < 2 ? (h == 0 ? w.x : w.y) : (h == 2 ? w.z : w.w);
}
DEV_INLINE float red16(float v){
  v += __shfl_xor(v, 1); v += __shfl_xor(v, 2);
  v += __shfl_xor(v, 4); v += __shfl_xor(v, 8);
  return v;
}

// ---------------- generic small MLP stage: out[2*OD] = act(in[2,K] @ W[K,OD] + b) ----------------
template<int K>
__global__ __launch_bounds__(256) void k_mlp(const float* __restrict__ in,
    const float* __restrict__ W, const float* __restrict__ bias,
    float* __restrict__ out, int OD, int doAct){
  int wave = threadIdx.x >> 6, lane = threadIdx.x & 63;
  int o = blockIdx.x*4 + wave;
  if (o >= 2*OD) return;
  int b = (o >= OD) ? 1 : 0;
  int j = o - b*OD;
  const float* __restrict__ ip = in + b*K;
  float acc = 0.f;
  #pragma unroll 2
  for (int k = lane; k < K; k += 64) acc += ip[k] * W[(size_t)k*OD + j];
  #pragma unroll
  for (int off = 32; off; off >>= 1) acc += __shfl_xor(acc, off);
  if (lane == 0){
    float v = acc + (bias ? bias[j] : 0.f);
    out[o] = doAct ? leaky(v) : v;
  }
}

// ---------------- zero int buffer ----------------
__global__ __launch_bounds__(256) void k_zero(int* __restrict__ p, int n){
  int i = blockIdx.x*256 + threadIdx.x;
  if (i < n) p[i] = 0;
}

// ---------------- ht0(bf16) = x @ gw0[:64,:] + styleW0[b] ----------------
__global__ __launch_bounds__(256) void k_ht0(const float* __restrict__ x,
    const float* __restrict__ gw0, const float* __restrict__ styleW0,
    ushort* __restrict__ ht0){
  __shared__ float wl[64][128];
  __shared__ float xl[32][64];
  __shared__ float sw[2][128];
  int t = threadIdx.x;
  for (int i=t; i<64*128; i+=256) wl[i>>7][i&127] = gw0[i];
  if (t < 256) sw[t>>7][t&127] = styleW0[t];
  int row0 = blockIdx.x*32;
  for (int i=t; i<32*64; i+=256){
    int r = i>>6, c = i&63; int gr = row0 + r;
    xl[r][c] = (gr < Nn) ? x[gr*64 + c] : 0.f;
  }
  __syncthreads();
  int c = t & 127, rh = t >> 7;
  float acc[16];
  #pragma unroll
  for (int i=0;i<16;i++) acc[i]=0.f;
  for (int k=0;k<64;k++){
    float w = wl[k][c];
    #pragma unroll
    for (int i=0;i<16;i++) acc[i] += xl[rh+2*i][k]*w;
  }
  float s0 = sw[0][c], s1 = sw[1][c];
  #pragma unroll
  for (int i=0;i<16;i++){
    int gr = row0 + rh + 2*i;
    if (gr < Nn){
      ht0[(size_t)gr*128 + c]      = f2bf(acc[i] + s0);
      ht0[(size_t)(Nn+gr)*128 + c] = f2bf(acc[i] + s1);
    }
  }
}

// ---- MFMA matmul + fused attention logits ----
// out[M,LDO](bf16) = A[M,128](bf16) @ W[128,NCOL](f32);
// alS/alD: per-row logits vs a_s/a_d (flat [NCOL]); NHEAD=4 -> float4 per row, NHEAD=1 -> scalar.
template<int NCOL, int LDO, int NF, int NHEAD>
__global__ __launch_bounds__(256) void k_mm_mfma(const ushort* __restrict__ A,
    const float* __restrict__ W, ushort* __restrict__ out,
    const float* __restrict__ a_s, const float* __restrict__ a_d,
    float* __restrict__ alS, float* __restrict__ alD, int M){
  constexpr int NCOLP = NF*16;
  __shared__ ushort bt[NCOLP*128];  // Bt[c][k], XOR-swizzled
  int t = threadIdx.x;
  int wid = t >> 6, lane = t & 63, l15 = lane & 15, g = lane >> 4;
  int mbase = blockIdx.x*128 + wid*32;

  bf16x8 afr[2][4];
  #pragma unroll
  for (int mf=0; mf<2; mf++){
    int row = mbase + mf*16 + l15;
    int rc = row < M ? row : M-1;
    const ushort* ap = A + (size_t)rc*128 + g*8;
    #pragma unroll
    for (int ks=0; ks<4; ks++)
      afr[mf][ks] = *(const bf16x8*)(ap + ks*32);
  }

  for (int idx = t; idx < 128*NCOLP; idx += 256){
    int k = idx / NCOLP, c = idx % NCOLP;
    float v = (c < NCOL) ? W[k*NCOL + c] : 0.f;
    uint byte = ((uint)(c*128 + k) << 1) ^ ((uint)(c&7) << 4);
    *(ushort*)((char*)bt + byte) = f2bf(v);
  }
  __syncthreads();

  f32x4 acc[2][NF];
  #pragma unroll
  for (int mf=0; mf<2; mf++)
    #pragma unroll
    for (int nf=0; nf<NF; nf++) acc[mf][nf] = (f32x4){0.f,0.f,0.f,0.f};

  #pragma unroll
  for (int ks=0; ks<4; ks++){
    int kb = ks*32 + g*8;
    bf16x8 bfr[NF];
    #pragma unroll
    for (int nf=0; nf<NF; nf++){
      int c = nf*16 + l15;
      uint byte = ((uint)(c*128 + kb) << 1) ^ ((uint)(c&7) << 4);
      bfr[nf] = *(const bf16x8*)((const char*)bt + byte);
    }
    #pragma unroll
    for (int mf=0; mf<2; mf++)
      #pragma unroll
      for (int nf=0; nf<NF; nf++)
        acc[mf][nf] = __builtin_amdgcn_mfma_f32_16x16x32_bf16(
            afr[mf][ks], bfr[nf], acc[mf][nf], 0, 0, 0);
  }

  // C/D layout: col = lane&15, row = (lane>>4)*4 + r
  #pragma unroll
  for (int mf=0; mf<2; mf++){
    int rbase = mbase + mf*16 + g*4;
    #pragma unroll
    for (int nf=0; nf<NF; nf++){
      int c = nf*16 + l15;
      if (c < LDO){
        #pragma unroll
        for (int r=0; r<4; r++){
          int row = rbase + r;
          if (row < M) out[(size_t)row*LDO + c] = (c < NCOL) ? f2bf(acc[mf][nf][r]) : (ushort)0;
        }
      }
    }
  }

  // fused per-row attention logits
  float as_v[NF], ad_v[NF];
  #pragma unroll
  for (int nf=0; nf<NF; nf++){
    int c = nf*16 + l15;
    as_v[nf] = (c < NCOL) ? a_s[c] : 0.f;
    ad_v[nf] = (c < NCOL) ? a_d[c] : 0.f;
  }
  #pragma unroll
  for (int mf=0; mf<2; mf++){
    #pragma unroll
    for (int r=0; r<4; r++){
      int row = mbase + mf*16 + g*4 + r;
      if (NHEAD == 4){
        float ps0 = acc[mf][0][r]*as_v[0] + acc[mf][1][r]*as_v[1];
        float ps1 = acc[mf][2][r]*as_v[2] + acc[mf][3][r]*as_v[3];
        float ps2 = acc[mf][4][r]*as_v[4] + acc[mf][5][r]*as_v[5];
        float ps3 = acc[mf][6][r]*as_v[6] + acc[mf][7][r]*as_v[7];
        float pd0 = acc[mf][0][r]*ad_v[0] + acc[mf][1][r]*ad_v[1];
        float pd1 = acc[mf][2][r]*ad_v[2] + acc[mf][3][r]*ad_v[3];
        float pd2 = acc[mf][4][r]*ad_v[4] + acc[mf][5][r]*ad_v[5];
        float pd3 = acc[mf][6][r]*ad_v[6] + acc[mf][7][r]*ad_v[7];
        ps0 = red16(ps0); ps1 = red16(ps1); ps2 = red16(ps2); ps3 = red16(ps3);
        pd0 = red16(pd0); pd1 = red16(pd1); pd2 = red16(pd2); pd3 = red16(pd3);
        if (l15 == 0 && row < M){
          *(float4*)(alS + (size_t)row*4) = make_float4(ps0, ps1, ps2, ps3);
          *(float4*)(alD + (size_t)row*4) = make_float4(pd0, pd1, pd2, pd3);
        }
      } else {
        float ps = 0.f, pd = 0.f;
        #pragma unroll
        for (int nf=0; nf<NF; nf++){
          ps += acc[mf][nf][r]*as_v[nf];
          pd += acc[mf][nf][r]*ad_v[nf];
        }
        ps = red16(ps); pd = red16(pd);
        if (l15 == 0 && row < M){
          alS[row] = ps; alD[row] = pd;
        }
      }
    }
  }
}

// ---------------- per-node attention logits (4 heads x 32), bf16 input (layer 0 only) ----------------
__global__ __launch_bounds__(256) void k_al(const ushort* __restrict__ ht,
    const float* __restrict__ a_s, const float* __restrict__ a_d,
    float* __restrict__ alS, float* __restrict__ alD, int n){
  int g = blockIdx.x*256 + threadIdx.x;
  if (g >= n*4) return;
  int node = g >> 2, h = g & 3;
  const ushort* row = ht + (size_t)node*128 + h*32;
  float s = 0.f, dd = 0.f;
  #pragma unroll
  for (int k=0;k<32;k++){ float v = bf2f(row[k]); s += v*a_s[h*32+k]; dd += v*a_d[h*32+k]; }
  alS[g] = s; alD[g] = dd;
}

// ---------------- CSR build (TEMPLATE graph only) ----------------
__global__ void k_hist(const int* __restrict__ eidx, int* __restrict__ cnt){
  int e = blockIdx.x*256 + threadIdx.x;
  if (e >= Me) return;
  atomicAdd(&cnt[eidx[Me + e]], 1);
}

// single-block exclusive scan of cnt[Nn] -> row_start (10 elems/thread, 1024 threads)
__global__ __launch_bounds__(1024) void k_scan(const int* __restrict__ cnt,
    int* __restrict__ row_start){
  __shared__ int wtot[16];
  int t = threadIdx.x, lane = t & 63, w = t >> 6;
  int base = t*10;
  int pre[10]; int sum = 0;
  #pragma unroll
  for (int q=0;q<10;q++){
    int i = base+q;
    int v = (i < Nn) ? cnt[i] : 0;
    pre[q] = sum; sum += v;
  }
  int incl = sum;
  #pragma unroll
  for (int d=1; d<64; d<<=1){
    int y = __shfl_up(incl, d);
    if (lane >= d) incl += y;
  }
  if (lane == 63) wtot[w] = incl;
  __syncthreads();
  int wbase = 0;
  #pragma unroll
  for (int k=0;k<16;k++) wbase += (k < w) ? wtot[k] : 0;
  int excl = wbase + incl - sum;
  #pragma unroll
  for (int q=0;q<10;q++){
    int i = base+q;
    if (i < Nn) row_start[i] = excl + pre[q];
  }
  if (t == 1023) row_start[Nn] = excl + sum;
}

__global__ void k_scatter(const int* __restrict__ eidx,
    const int* __restrict__ row_start, int* __restrict__ cursor,
    int* __restrict__ csr){
  int e = blockIdx.x*256 + threadIdx.x;
  if (e >= Me) return;
  int s = eidx[e], d = eidx[Me + e];
  int p = row_start[d] + atomicAdd(&cursor[d], 1);
  csr[p] = s;
}

// ---------------- GAT aggregation layer 0/1, bf16 gathers, paired cols ----------------
__global__ __launch_bounds__(256) void k_gat128(const ushort* __restrict__ ht,
    const float* __restrict__ alS, const float* __restrict__ alD,
    const int* __restrict__ row_start, const int* __restrict__ csr,
    const float* __restrict__ gb, const float* __restrict__ lng,
    const float* __restrict__ lnb, ushort* __restrict__ outH, int n){
  __shared__ float4 wbuf[4][64];
  __shared__ int    sbuf[4][64];
  int wave = threadIdx.x >> 6, lane = threadIdx.x & 63;
  int dd = blockIdx.x*4 + wave;
  if (dd >= n) return;
  int tr  = (dd >= Nn) ? dd - Nn : dd;
  int off = (dd >= Nn) ? Nn : 0;
  int c0 = lane*2;
  int h  = lane >> 4;
  float4 ald4 = *(const float4*)(alD + dd*4);
  int begin = row_start[tr], end = row_start[tr+1];

  // self-loop term
  float4 asl = *(const float4*)(alS + dd*4);
  float4 wsl;
  wsl.x = __expf(leaky(asl.x + ald4.x));
  wsl.y = __expf(leaky(asl.y + ald4.y));
  wsl.z = __expf(leaky(asl.z + ald4.z));
  wsl.w = __expf(leaky(asl.w + ald4.w));
  float es = sel4(wsl, h);
  uint sv0 = *(const uint*)(ht + (size_t)dd*128 + c0);
  float den  = es;
  float acc0 = es * bf2f((ushort)(sv0 & 0xffff));
  float acc1 = es * bf2f((ushort)(sv0 >> 16));

  const ushort* __restrict__ htp = ht + c0;

  for (int j = begin; j < end; j += 64){
    int nc = min(64, end - j);
    // phase A: one edge per lane -> 4-head weights into wave-private LDS
    if (lane < nc){
      int s = csr[j + lane] + off;
      float4 as4 = *(const float4*)(alS + s*4);
      float4 w;
      w.x = __expf(leaky(as4.x + ald4.x));
      w.y = __expf(leaky(as4.y + ald4.y));
      w.z = __expf(leaky(as4.z + ald4.z));
      w.w = __expf(leaky(as4.w + ald4.w));
      wbuf[wave][lane] = w;
      sbuf[wave][lane] = s;
    }
    // phase B: column-parallel FMA (LDS reads broadcast)
    int q = 0;
    for (; q + 8 <= nc; q += 8){
      int sv[8]; float4 wv[8];
      #pragma unroll
      for (int u=0;u<8;u++){ sv[u] = sbuf[wave][q+u]; wv[u] = wbuf[wave][q+u]; }
      uint hv[8];
      #pragma unroll
      for (int u=0;u<8;u++) hv[u] = *(const uint*)(htp + (size_t)sv[u]*128);
      #pragma unroll
      for (int u=0;u<8;u++){
        float e = sel4(wv[u], h);
        den  += e;
        acc0 += e * bf2f((ushort)(hv[u] & 0xffff));
        acc1 += e * bf2f((ushort)(hv[u] >> 16));
      }
    }
    for (; q < nc; q++){
      int s = sbuf[wave][q];
      float e = sel4(wbuf[wave][q], h);
      uint hv = *(const uint*)(htp + (size_t)s*128);
      den  += e;
      acc0 += e * bf2f((ushort)(hv & 0xffff));
      acc1 += e * bf2f((ushort)(hv >> 16));
    }
  }
  float idn = 1.f / (den + 1e-16f);
  float v0 = acc0*idn + gb[c0];
  float v1 = acc1*idn + gb[c0+1];

  // LayerNorm over 128 features held by this wave (2 per lane)
  float sum = v0 + v1, sq = v0*v0 + v1*v1;
  #pragma unroll
  for (int offx = 32; offx; offx >>= 1){
    sum += __shfl_xor(sum, offx);
    sq  += __shfl_xor(sq,  offx);
  }
  float mu  = sum * (1.f/128.f);
  float var = sq  * (1.f/128.f) - mu*mu;
  float inv = rsqrtf(var + 1e-5f);
  float y0 = (v0 - mu)*inv*lng[c0]   + lnb[c0];
  float y1 = (v1 - mu)*inv*lng[c0+1] + lnb[c0+1];
  uint ow = (uint)f2bf(leaky(y0)) | ((uint)f2bf(leaky(y1)) << 16);
  *(uint*)(outH + (size_t)dd*128 + c0) = ow;
}

// ---------------- GAT output layer (1 head, 67 cols), bf16 gathers + residual ----------------
__global__ __launch_bounds__(256) void k_gat_out(const ushort* __restrict__ ht2,
    const float* __restrict__ alS, const float* __restrict__ alD,
    const int* __restrict__ row_start, const int* __restrict__ csr,
    const float* __restrict__ gb2, const float* __restrict__ x,
    const float* __restrict__ pos, float* __restrict__ out, int n){
  __shared__ float wbuf[4][64];
  __shared__ int   sbuf[4][64];
  int wave = threadIdx.x >> 6, lane = threadIdx.x & 63;
  int dd = blockIdx.x*4 + wave;
  if (dd >= n) return;
  int tr  = (dd >= Nn) ? dd - Nn : dd;
  int off = (dd >= Nn) ? Nn : 0;
  int c0 = lane*2;
  bool act = (c0 < 67);             // lane < 34
  float ald = alD[dd];
  int begin = row_start[tr], end = row_start[tr+1];

  // self-loop term
  float wsl = __expf(leaky(alS[dd] + ald));
  float den  = wsl;
  uint sv0 = act ? *(const uint*)(ht2 + (size_t)dd*68 + c0) : 0u;
  float acc0 = wsl * bf2f((ushort)(sv0 & 0xffff));
  float acc1 = wsl * bf2f((ushort)(sv0 >> 16));

  const ushort* __restrict__ h2p = ht2 + c0;

  for (int j = begin; j < end; j += 64){
    int nc = min(64, end - j);
    if (lane < nc){
      int s = csr[j + lane] + off;
      wbuf[wave][lane] = __expf(leaky(alS[s] + ald));
      sbuf[wave][lane] = s;
    }
    int q = 0;
    for (; q + 8 <= nc; q += 8){
      int sv[8]; float wv[8];
      #pragma unroll
      for (int u=0;u<8;u++){ sv[u] = sbuf[wave][q+u]; wv[u] = wbuf[wave][q+u]; }
      uint hv[8];
      #pragma unroll
      for (int u=0;u<8;u++) hv[u] = act ? *(const uint*)(h2p + (size_t)sv[u]*68) : 0u;
      #pragma unroll
      for (int u=0;u<8;u++){
        den  += wv[u];
        acc0 += wv[u] * bf2f((ushort)(hv[u] & 0xffff));
        acc1 += wv[u] * bf2f((ushort)(hv[u] >> 16));
      }
    }
    for (; q < nc; q++){
      int s = sbuf[wave][q]; float w = wbuf[wave][q];
      uint hv = act ? *(const uint*)(h2p + (size_t)s*68) : 0u;
      den  += w;
      acc0 += w * bf2f((ushort)(hv & 0xffff));
      acc1 += w * bf2f((ushort)(hv >> 16));
    }
  }
  if (!act) return;
  float idn = 1.f / (den + 1e-16f);
  int i = tr;
  int c1 = c0 + 1;
  float v0 = acc0*idn + gb2[c0];
  if (c0 < 3) out[NT*64 + dd*3 + c0] = pos[i*3 + c0] + v0;
  else        out[dd*64 + (c0-3)]    = x[i*64 + (c0-3)] + v0;
  if (c1 < 67){
    float v1 = acc1*idn + gb2[c1];
    if (c1 < 3) out[NT*64 + dd*3 + c1] = pos[i*3 + c1] + v1;
    else        out[dd*64 + (c1-3)]    = x[i*64 + (c1-3)] + v1;
  }
}

extern "C" void kernel_launch(void* const* d_in, const int* in_sizes, int n_in,
                              void* d_out, int out_size, void* d_ws, size_t ws_size,
                              hipStream_t stream){
  const float* z    = (const float*)d_in[0];
  const float* x    = (const float*)d_in[1];
  const float* pos  = (const float*)d_in[2];
  const int*   eidx = (const int*)  d_in[3];
  const float* w1   = (const float*)d_in[4];
  const float* b1   = (const float*)d_in[5];
  const float* w2   = (const float*)d_in[6];
  const float* b2   = (const float*)d_in[7];
  const float* w3   = (const float*)d_in[8];
  const float* b3   = (const float*)d_in[9];
  const float* gw0  = (const float*)d_in[10];
  const float* ga0s = (const float*)d_in[11];
  const float* ga0d = (const float*)d_in[12];
  const float* gb0  = (const float*)d_in[13];
  const float* gw1  = (const float*)d_in[14];
  const float* ga1s = (const float*)d_in[15];
  const float* ga1d = (const float*)d_in[16];
  const float* gb1  = (const float*)d_in[17];
  const float* gw2  = (const float*)d_in[18];
  const float* ga2s = (const float*)d_in[19];
  const float* ga2d = (const float*)d_in[20];
  const float* gb2  = (const float*)d_in[21];
  const float* ln0g = (const float*)d_in[22];
  const float* ln0b = (const float*)d_in[23];
  const float* ln1g = (const float*)d_in[24];
  const float* ln1b = (const float*)d_in[25];
  float* out = (float*)d_out;

  float* ws       = (float*)d_ws;
  float* styleW0  = ws;                  // 256
  float* s1buf    = ws + 256;            // 512
  float* s2buf    = s1buf + 512;         // 1024
  float* stbuf    = s2buf + 1024;        // 256
  float* alS      = stbuf + 256;         // 80000
  float* alD      = alS + 80000;         // 80000
  ushort* htA     = (ushort*)(alD + 80000);  // NT*128 bf16
  ushort* htB     = htA + (size_t)NT*128;    // NT*128 bf16
  ushort* ht2c    = htB + (size_t)NT*128;    // NT*68 bf16
  int*   cnt      = (int*)(ht2c + (size_t)NT*68); // Nn
  int*   cursor   = cnt + Nn;                // Nn
  int*   row_start= cursor + Nn;             // Nn+1
  int*   csr      = row_start + Nn + 1;      // Me

  // style path: z[2,128] -> s1[2,256] -> s2[2,512] -> style[2,128] -> styleW0[2,128]
  k_mlp<128><<<(2*256+3)/4, 256, 0, stream>>>(z,     w1, b1, s1buf, 256, 1);
  k_mlp<256><<<(2*512+3)/4, 256, 0, stream>>>(s1buf, w2, b2, s2buf, 512, 1);
  k_mlp<512><<<(2*128+3)/4, 256, 0, stream>>>(s2buf, w3, b3, stbuf, 128, 0);
  k_mlp<128><<<(2*128+3)/4, 256, 0, stream>>>(stbuf, gw0 + 64*128, (const float*)nullptr, styleW0, 128, 0);

  // CSR by dst (template graph only)
  k_zero<<<(2*Nn+255)/256, 256, 0, stream>>>(cnt, 2*Nn);   // cnt + cursor (contiguous)
  k_hist<<<(Me+255)/256, 256, 0, stream>>>(eidx, cnt);
  k_scan<<<1, 1024, 0, stream>>>(cnt, row_start);
  k_scatter<<<(Me+255)/256, 256, 0, stream>>>(eidx, row_start, cursor, csr);

  const int MB = (NT+127)/128;
  // layer 0
  k_ht0<<<(Nn+31)/32, 256, 0, stream>>>(x, gw0, styleW0, htA);
  k_al<<<(NT*4+255)/256, 256, 0, stream>>>(htA, ga0s, ga0d, alS, alD, NT);
  k_gat128<<<(NT+3)/4, 256, 0, stream>>>(htA, alS, alD, row_start, csr,
                                         gb0, ln0g, ln0b, htB, NT);
  // layer 1 (matmul + fused logits for layer-1 attention)
  k_mm_mfma<128,128,8,4><<<MB, 256, 0, stream>>>(htB, gw1, htA, ga1s, ga1d, alS, alD, NT);
  k_gat128<<<(NT+3)/4, 256, 0, stream>>>(htA, alS, alD, row_start, csr,
                                         gb1, ln1g, ln1b, htB, NT);
  // layer 2 (matmul + fused logits, 1 head; then fused residual + final write)
  k_mm_mfma<67,68,5,1><<<MB, 256, 0, stream>>>(htB, gw2, ht2c, ga2s, ga2d, alS, alD, NT);
  k_gat_out<<<(NT+3)/4, 256, 0, stream>>>(ht2c, alS, alD, row_start, csr,
                                          gb2, x, pos, out, NT);
}